// Round 1
// baseline (1881.782 us; speedup 1.0000x reference)
//
#include <hip/hip_runtime.h>
#include <hip/hip_bf16.h>

#define NB 8
#define NS 256
#define ND 512
#define NH 8
#define NDH 64
#define NFF 2048
#define NE 8
#define NV 32000
#define NRH 256
#define MAXV 2
#define NEGV (-1e9f)

typedef __attribute__((ext_vector_type(8))) short short8;
typedef __attribute__((ext_vector_type(4))) float f32x4;

__device__ __forceinline__ unsigned short f2bf(float x) {
  unsigned int u = __float_as_uint(x);
  u = (u + 0x7fffu + ((u >> 16) & 1u)) >> 16;
  return (unsigned short)u;
}

// ---------------- state init ----------------
__global__ void k_init(int* visits, int* active, float* ent) {
  int t = threadIdx.x;
  if (t < NB * NE) visits[t] = 0;
  if (t < NB) active[t] = 1;
  if (t == 0) *ent = 0.f;
}

// ---------------- embedding ----------------
__global__ __launch_bounds__(256) void k_embed(const int* __restrict__ ids,
                                               const float* __restrict__ emb,
                                               const float* __restrict__ pe,
                                               float* __restrict__ rep) {
  int bs = blockIdx.x;               // b*NS + s
  int s = bs & (NS - 1);
  int id = ids[bs];
  const float sc = (id != 0) ? 22.627416997969522f : 0.f;  // sqrt(512), pad row zeroed
  const float* er = emb + (size_t)id * ND;
  const float* per = pe + (size_t)s * ND;
  float* out = rep + (size_t)bs * ND;
  for (int d = threadIdx.x; d < ND; d += 256)
    out[d] = er[d] * sc + per[d];
}

// ---------------- summary = rep.mean(1) ----------------
__global__ __launch_bounds__(256) void k_summary(const float* __restrict__ rep,
                                                 float* __restrict__ summ) {
  int b = blockIdx.x >> 1;
  int d = ((blockIdx.x & 1) << 8) + threadIdx.x;
  const float* r = rep + ((size_t)b * NS) * ND + d;
  float acc = 0.f;
  for (int s = 0; s < NS; ++s) acc += r[(size_t)s * ND];
  summ[b * ND + d] = acc * (1.f / NS);
}

// ---------------- router (1 block) ----------------
__global__ __launch_bounds__(256) void k_router(const float* __restrict__ summ,
                                                const float* __restrict__ rw1,
                                                const float* __restrict__ rb1,
                                                const float* __restrict__ rw2,
                                                const float* __restrict__ rb2,
                                                int* visits, int* active,
                                                int* idx, int* go, float* ent_total) {
  __shared__ float sm[NB][ND];
  __shared__ float h[NB][NRH];
  __shared__ float lg[NB][NE + 1];
  int t = threadIdx.x;
  for (int i = t; i < NB * ND; i += 256) sm[i >> 9][i & 511] = summ[i];
  __syncthreads();
  // hidden layer: thread t = neuron t, all batches
  {
    const float* w = rw1 + (size_t)t * ND;
    float acc[NB];
#pragma unroll
    for (int b = 0; b < NB; ++b) acc[b] = rb1[t];
    for (int d = 0; d < ND; ++d) {
      float wv = w[d];
#pragma unroll
      for (int b = 0; b < NB; ++b) acc[b] += sm[b][d] * wv;
    }
#pragma unroll
    for (int b = 0; b < NB; ++b) h[b][t] = fmaxf(acc[b], 0.f);
  }
  __syncthreads();
  if (t < NB * (NE + 1)) {
    int b = t / (NE + 1), e = t % (NE + 1);
    const float* w = rw2 + e * NRH;
    float a = rb2[e];
    for (int r = 0; r < NRH; ++r) a += h[b][r] * w[r];
    lg[b][e] = a;
  }
  __syncthreads();
  if (t == 0) {
    int aprev[NB];
    int cnt = 0;
    for (int b = 0; b < NB; ++b) { aprev[b] = active[b]; cnt += aprev[b]; }
    float entsum = 0.f;
    for (int b = 0; b < NB; ++b) {
      float l[NE + 1];
      for (int e = 0; e < NE; ++e)
        l[e] = (visits[b * NE + e] >= MAXV) ? NEGV : lg[b][e];
      l[NE] = lg[b][NE];
      float m = l[0];
      for (int e = 1; e <= NE; ++e) m = fmaxf(m, l[e]);
      float z = 0.f, p[NE + 1];
      for (int e = 0; e <= NE; ++e) { p[e] = __expf(l[e] - m); z += p[e]; }
      float zi = 1.f / z, ent = 0.f;
      for (int e = 0; e <= NE; ++e) {
        float pp = p[e] * zi;
        ent -= pp * __logf(pp + 1e-9f);
      }
      if (aprev[b]) entsum += ent;
      int ch = 0; float bm = l[0];
      for (int e = 1; e <= NE; ++e) if (l[e] > bm) { bm = l[e]; ch = e; }
      int g = (aprev[b] && ch < NE) ? 1 : 0;
      int ix = g ? ch : 0;
      visits[b * NE + ix] += g;
      idx[b] = ix; go[b] = g; active[b] = g;
    }
    if (cnt > 0) *ent_total += entsum / (float)cnt;
  }
}

// ---------------- generic fp32 expert GEMM: O = X @ W[idx].T + bias[idx] ----------------
template <int BRELU>
__global__ __launch_bounds__(256) void k_gemm_expert(
    const float* __restrict__ Xall, int sx,
    const float* __restrict__ Wall, const float* __restrict__ ball,
    float* __restrict__ Oall, int so, int N, int K,
    const int* __restrict__ go, const int* __restrict__ idx) {
  int b = blockIdx.z;
  if (!go[b]) return;
  const float* X = Xall + (size_t)b * sx;
  const float* W = Wall + (size_t)idx[b] * N * K;
  const float* bias = ball + (size_t)idx[b] * N;
  float* O = Oall + (size_t)b * so;
  int bm = blockIdx.x * 64, bn = blockIdx.y * 64;
  __shared__ float Xs[16][68];
  __shared__ float Ws[16][68];
  int t = threadIdx.x;
  int tx = t & 15, ty = t >> 4;
  int lr = t >> 2, lc = (t & 3) * 4;
  float acc[4][4] = {};
  for (int k0 = 0; k0 < K; k0 += 16) {
    float4 xa = *(const float4*)&X[(size_t)(bm + lr) * K + k0 + lc];
    float4 wa = *(const float4*)&W[(size_t)(bn + lr) * K + k0 + lc];
    __syncthreads();
    Xs[lc + 0][lr] = xa.x; Xs[lc + 1][lr] = xa.y; Xs[lc + 2][lr] = xa.z; Xs[lc + 3][lr] = xa.w;
    Ws[lc + 0][lr] = wa.x; Ws[lc + 1][lr] = wa.y; Ws[lc + 2][lr] = wa.z; Ws[lc + 3][lr] = wa.w;
    __syncthreads();
#pragma unroll
    for (int kk = 0; kk < 16; ++kk) {
      float a0 = Xs[kk][ty * 4 + 0], a1 = Xs[kk][ty * 4 + 1];
      float a2 = Xs[kk][ty * 4 + 2], a3 = Xs[kk][ty * 4 + 3];
      float b0 = Ws[kk][tx * 4 + 0], b1 = Ws[kk][tx * 4 + 1];
      float b2 = Ws[kk][tx * 4 + 2], b3 = Ws[kk][tx * 4 + 3];
      acc[0][0] += a0 * b0; acc[0][1] += a0 * b1; acc[0][2] += a0 * b2; acc[0][3] += a0 * b3;
      acc[1][0] += a1 * b0; acc[1][1] += a1 * b1; acc[1][2] += a1 * b2; acc[1][3] += a1 * b3;
      acc[2][0] += a2 * b0; acc[2][1] += a2 * b1; acc[2][2] += a2 * b2; acc[2][3] += a2 * b3;
      acc[3][0] += a3 * b0; acc[3][1] += a3 * b1; acc[3][2] += a3 * b2; acc[3][3] += a3 * b3;
    }
  }
#pragma unroll
  for (int i = 0; i < 4; ++i) {
    size_t ro = (size_t)(bm + ty * 4 + i) * N + bn;
#pragma unroll
    for (int j = 0; j < 4; ++j) {
      float v = acc[i][j] + bias[bn + tx * 4 + j];
      if (BRELU) v = fmaxf(v, 0.f);
      O[ro + tx * 4 + j] = v;
    }
  }
}

// ---------------- attention: one block per (i, h, b) ----------------
__global__ __launch_bounds__(256) void k_attn(const float* __restrict__ qkv,
                                              float* __restrict__ ctx,
                                              const int* __restrict__ go) {
  int b = blockIdx.z;
  if (!go[b]) return;
  int h = blockIdx.y, i = blockIdx.x;
  const float* qb = qkv + ((size_t)b * NS) * (3 * ND);
  __shared__ float q[NDH];
  __shared__ float p[NS];
  __shared__ float red[256];
  int t = threadIdx.x;
  if (t < NDH) q[t] = qb[(size_t)i * (3 * ND) + h * NDH + t];
  __syncthreads();
  const float* kr = qb + ND + h * NDH + (size_t)t * (3 * ND);
  float s = 0.f;
#pragma unroll
  for (int d = 0; d < NDH; d += 4) {
    float4 kv = *(const float4*)&kr[d];
    s += q[d] * kv.x + q[d + 1] * kv.y + q[d + 2] * kv.z + q[d + 3] * kv.w;
  }
  s *= 0.125f;  // 1/sqrt(64)
  red[t] = s; __syncthreads();
  for (int off = 128; off > 0; off >>= 1) {
    if (t < off) red[t] = fmaxf(red[t], red[t + off]);
    __syncthreads();
  }
  float m = red[0];
  __syncthreads();
  float e = __expf(s - m);
  p[t] = e; red[t] = e; __syncthreads();
  for (int off = 128; off > 0; off >>= 1) {
    if (t < off) red[t] += red[t + off];
    __syncthreads();
  }
  float zinv = 1.f / red[0];
  __syncthreads();
  int g4 = t >> 6, d = t & 63;
  const float* vr = qb + 2 * ND + h * NDH + d + (size_t)(g4 * 64) * (3 * ND);
  float acc = 0.f;
#pragma unroll 8
  for (int j = 0; j < 64; ++j) acc += p[g4 * 64 + j] * vr[(size_t)j * (3 * ND)];
  red[t] = acc; __syncthreads();
  if (t < 64) {
    float r = (red[t] + red[t + 64] + red[t + 128] + red[t + 192]) * zinv;
    ctx[((size_t)b * NS + i) * ND + h * NDH + t] = r;
  }
}

// ---------------- residual + LayerNorm (+optional tag) ----------------
__global__ __launch_bounds__(256) void k_ln(const float* __restrict__ xin,
                                            const float* __restrict__ yin,
                                            const float* __restrict__ gall,
                                            const float* __restrict__ ball,
                                            const float* __restrict__ tagall,
                                            float* __restrict__ out,
                                            const int* __restrict__ go,
                                            const int* __restrict__ idx) {
  int b = blockIdx.y;
  if (!go[b]) return;
  int s = blockIdx.x;
  size_t base = ((size_t)b * NS + s) * ND;
  int t = threadIdx.x;
  float v0 = xin[base + t] + yin[base + t];
  float v1 = xin[base + t + 256] + yin[base + t + 256];
  __shared__ float red[256];
  red[t] = v0 + v1; __syncthreads();
  for (int off = 128; off > 0; off >>= 1) {
    if (t < off) red[t] += red[t + off];
    __syncthreads();
  }
  float mu = red[0] * (1.f / ND);
  __syncthreads();
  float d0 = v0 - mu, d1 = v1 - mu;
  red[t] = d0 * d0 + d1 * d1; __syncthreads();
  for (int off = 128; off > 0; off >>= 1) {
    if (t < off) red[t] += red[t + off];
    __syncthreads();
  }
  float rs = rsqrtf(red[0] * (1.f / ND) + 1e-5f);
  int ix = idx[b];
  const float* g = gall + ix * ND;
  const float* bb = ball + ix * ND;
  float t0 = 0.f, t1 = 0.f;
  if (tagall) { t0 = tagall[ix * ND + t]; t1 = tagall[ix * ND + t + 256]; }
  out[base + t] = d0 * rs * g[t] + bb[t] + t0;
  out[base + t + 256] = d1 * rs * g[t + 256] + bb[t + 256] + t1;
}

// ---------------- LM head: bf16 MFMA GEMM, C[2048][32000] = A[2048][512] @ W[32000][512]^T + b ----------------
__global__ __launch_bounds__(256) void k_lmhead(const float* __restrict__ A,
                                                const float* __restrict__ W,
                                                const float* __restrict__ bias,
                                                float* __restrict__ out) {
  __shared__ __align__(16) unsigned short As[128][48];
  __shared__ __align__(16) unsigned short Bs[128][48];
  int t = threadIdx.x;
  int lane = t & 63, wave = t >> 6;
  int wm = (wave >> 1) * 64, wn = (wave & 1) * 64;
  int bm = blockIdx.x * 128, bn = blockIdx.y * 128;
  f32x4 acc[4][4];
#pragma unroll
  for (int i = 0; i < 4; ++i)
#pragma unroll
    for (int j = 0; j < 4; ++j) acc[i][j] = (f32x4){0.f, 0.f, 0.f, 0.f};

  for (int k0 = 0; k0 < ND; k0 += 32) {
    __syncthreads();
#pragma unroll
    for (int u = 0; u < 4; ++u) {
      int f = t + u * 256;
      int r = f >> 3, c = (f & 7) * 4;
      float4 av = *(const float4*)&A[(size_t)(bm + r) * ND + k0 + c];
      As[r][c + 0] = f2bf(av.x); As[r][c + 1] = f2bf(av.y);
      As[r][c + 2] = f2bf(av.z); As[r][c + 3] = f2bf(av.w);
      float4 wv = *(const float4*)&W[(size_t)(bn + r) * ND + k0 + c];
      Bs[r][c + 0] = f2bf(wv.x); Bs[r][c + 1] = f2bf(wv.y);
      Bs[r][c + 2] = f2bf(wv.z); Bs[r][c + 3] = f2bf(wv.w);
    }
    __syncthreads();
    short8 a[4], bfr[4];
    int row0 = (lane & 15), kof = (lane >> 4) * 8;
#pragma unroll
    for (int mf = 0; mf < 4; ++mf)
      a[mf] = *(const short8*)&As[wm + mf * 16 + row0][kof];
#pragma unroll
    for (int nf = 0; nf < 4; ++nf)
      bfr[nf] = *(const short8*)&Bs[wn + nf * 16 + row0][kof];
#pragma unroll
    for (int mf = 0; mf < 4; ++mf)
#pragma unroll
      for (int nf = 0; nf < 4; ++nf)
        acc[mf][nf] = __builtin_amdgcn_mfma_f32_16x16x32_bf16(a[mf], bfr[nf], acc[mf][nf], 0, 0, 0);
  }
  int lrow = (lane >> 4) * 4, lcol = lane & 15;
#pragma unroll
  for (int nf = 0; nf < 4; ++nf) {
    int col = bn + wn + nf * 16 + lcol;
    float bv = bias[col];
#pragma unroll
    for (int mf = 0; mf < 4; ++mf) {
#pragma unroll
      for (int r = 0; r < 4; ++r) {
        int row = bm + wm + mf * 16 + lrow + r;
        out[(size_t)row * NV + col] = acc[mf][nf][r] + bv;
      }
    }
  }
}

__global__ void k_ent(const float* __restrict__ entp, float* __restrict__ dst) {
  *dst = *entp;
}

extern "C" void kernel_launch(void* const* d_in, const int* in_sizes, int n_in,
                              void* d_out, int out_size, void* d_ws, size_t ws_size,
                              hipStream_t stream) {
  const int* ids   = (const int*)d_in[0];
  const float* emb = (const float*)d_in[1];
  const float* pe  = (const float*)d_in[2];
  const float* Wqkv = (const float*)d_in[3];
  const float* bqkv = (const float*)d_in[4];
  const float* Wo   = (const float*)d_in[5];
  const float* bo   = (const float*)d_in[6];
  const float* W1   = (const float*)d_in[7];
  const float* b1   = (const float*)d_in[8];
  const float* W2   = (const float*)d_in[9];
  const float* b2   = (const float*)d_in[10];
  const float* g1   = (const float*)d_in[11];
  const float* be1  = (const float*)d_in[12];
  const float* g2   = (const float*)d_in[13];
  const float* be2  = (const float*)d_in[14];
  const float* tag  = (const float*)d_in[15];
  const float* rw1  = (const float*)d_in[16];
  const float* rb1  = (const float*)d_in[17];
  const float* rw2  = (const float*)d_in[18];
  const float* rb2  = (const float*)d_in[19];
  const float* lmw  = (const float*)d_in[20];
  const float* lmb  = (const float*)d_in[21];
  float* out = (float*)d_out;

  float* ws = (float*)d_ws;
  size_t o = 0;
  float* rep = ws + o;  o += (size_t)NB * NS * ND;
  float* x1  = ws + o;  o += (size_t)NB * NS * ND;
  float* qkv = ws + o;  o += (size_t)NB * NS * 3 * ND;
  float* ctx = ws + o;  o += (size_t)NB * NS * ND;
  float* hid = ws + o;  o += (size_t)NB * NS * NFF;
  float* tmp = ws + o;  o += (size_t)NB * NS * ND;
  float* summ = ws + o; o += NB * ND;
  int* visits = (int*)(ws + o);
  int* active = visits + NB * NE;
  int* idx = active + NB;
  int* go = idx + NB;
  float* entp = (float*)(go + NB);

  k_init<<<1, 64, 0, stream>>>(visits, active, entp);
  k_embed<<<NB * NS, 256, 0, stream>>>(ids, emb, pe, rep);

  for (int step = 0; step < 4; ++step) {
    k_summary<<<NB * 2, 256, 0, stream>>>(rep, summ);
    k_router<<<1, 256, 0, stream>>>(summ, rw1, rb1, rw2, rb2,
                                    visits, active, idx, go, entp);
    // qkv = rep @ Wqkv^T + bqkv
    k_gemm_expert<0><<<dim3(4, 24, NB), 256, 0, stream>>>(
        rep, NS * ND, Wqkv, bqkv, qkv, NS * 3 * ND, 3 * ND, ND, go, idx);
    // attention
    k_attn<<<dim3(NS, NH, NB), 256, 0, stream>>>(qkv, ctx, go);
    // attn_out = ctx @ Wo^T + bo
    k_gemm_expert<0><<<dim3(4, 8, NB), 256, 0, stream>>>(
        ctx, NS * ND, Wo, bo, tmp, NS * ND, ND, ND, go, idx);
    // x1 = LN(rep + attn_out)
    k_ln<<<dim3(NS, NB), 256, 0, stream>>>(rep, tmp, g1, be1, nullptr, x1, go, idx);
    // hid = relu(x1 @ W1^T + b1)
    k_gemm_expert<1><<<dim3(4, 32, NB), 256, 0, stream>>>(
        x1, NS * ND, W1, b1, hid, NS * NFF, NFF, ND, go, idx);
    // ff = hid @ W2^T + b2
    k_gemm_expert<0><<<dim3(4, 8, NB), 256, 0, stream>>>(
        hid, NS * NFF, W2, b2, tmp, NS * ND, ND, NFF, go, idx);
    // rep = LN(x1 + ff) + tag   (written only where go)
    k_ln<<<dim3(NS, NB), 256, 0, stream>>>(x1, tmp, g2, be2, tag, rep, go, idx);
  }

  k_lmhead<<<dim3(2048 / 128, NV / 128), 256, 0, stream>>>(rep, lmw, lmb, out);
  k_ent<<<1, 1, 0, stream>>>(entp, out + (size_t)NB * NS * NV);
}

// Round 3
// 1579.597 us; speedup vs baseline: 1.1913x; 1.1913x over previous
//
#include <hip/hip_runtime.h>
#include <hip/hip_bf16.h>

#define NB 8
#define NS 256
#define ND 512
#define NH 8
#define NDH 64
#define NFF 2048
#define NE 8
#define NV 32000
#define NRH 256
#define MAXV 2
#define NEGV (-1e9f)

typedef __attribute__((ext_vector_type(8))) short short8;
typedef __attribute__((ext_vector_type(4))) float f32x4;

__device__ __forceinline__ unsigned short f2bf(float x) {
  unsigned int u = __float_as_uint(x);
  u = (u + 0x7fffu + ((u >> 16) & 1u)) >> 16;
  return (unsigned short)u;
}

// ---------------- state init ----------------
__global__ void k_init(int* visits, int* active, float* ent) {
  int t = threadIdx.x;
  if (t < NB * NE) visits[t] = 0;
  if (t < NB) active[t] = 1;
  if (t == 0) *ent = 0.f;
}

// ---------------- embedding ----------------
__global__ __launch_bounds__(256) void k_embed(const int* __restrict__ ids,
                                               const float* __restrict__ emb,
                                               const float* __restrict__ pe,
                                               float* __restrict__ rep) {
  int bs = blockIdx.x;               // b*NS + s
  int s = bs & (NS - 1);
  int id = ids[bs];
  const float sc = (id != 0) ? 22.627416997969522f : 0.f;  // sqrt(512), pad row zeroed
  const float* er = emb + (size_t)id * ND;
  const float* per = pe + (size_t)s * ND;
  float* out = rep + (size_t)bs * ND;
  for (int d = threadIdx.x; d < ND; d += 256)
    out[d] = er[d] * sc + per[d];
}

// ---------------- summary = rep.mean(1) ----------------
__global__ __launch_bounds__(256) void k_summary(const float* __restrict__ rep,
                                                 float* __restrict__ summ) {
  int b = blockIdx.x >> 1;
  int d = ((blockIdx.x & 1) << 8) + threadIdx.x;
  const float* r = rep + ((size_t)b * NS) * ND + d;
  float acc = 0.f;
  for (int s = 0; s < NS; ++s) acc += r[(size_t)s * ND];
  summ[b * ND + d] = acc * (1.f / NS);
}

// ---------------- router (1 block) ----------------
__global__ __launch_bounds__(256) void k_router(const float* __restrict__ summ,
                                                const float* __restrict__ rw1,
                                                const float* __restrict__ rb1,
                                                const float* __restrict__ rw2,
                                                const float* __restrict__ rb2,
                                                int* visits, int* active,
                                                int* idx, int* go, float* ent_total) {
  __shared__ float sm[NB][ND];
  __shared__ float h[NB][NRH];
  __shared__ float lg[NB][NE + 1];
  int t = threadIdx.x;
  for (int i = t; i < NB * ND; i += 256) sm[i >> 9][i & 511] = summ[i];
  __syncthreads();
  {
    const float* w = rw1 + (size_t)t * ND;
    float acc[NB];
#pragma unroll
    for (int b = 0; b < NB; ++b) acc[b] = rb1[t];
    for (int d = 0; d < ND; ++d) {
      float wv = w[d];
#pragma unroll
      for (int b = 0; b < NB; ++b) acc[b] += sm[b][d] * wv;
    }
#pragma unroll
    for (int b = 0; b < NB; ++b) h[b][t] = fmaxf(acc[b], 0.f);
  }
  __syncthreads();
  if (t < NB * (NE + 1)) {
    int b = t / (NE + 1), e = t % (NE + 1);
    const float* w = rw2 + e * NRH;
    float a = rb2[e];
    for (int r = 0; r < NRH; ++r) a += h[b][r] * w[r];
    lg[b][e] = a;
  }
  __syncthreads();
  if (t == 0) {
    int aprev[NB];
    int cnt = 0;
    for (int b = 0; b < NB; ++b) { aprev[b] = active[b]; cnt += aprev[b]; }
    float entsum = 0.f;
    for (int b = 0; b < NB; ++b) {
      float l[NE + 1];
      for (int e = 0; e < NE; ++e)
        l[e] = (visits[b * NE + e] >= MAXV) ? NEGV : lg[b][e];
      l[NE] = lg[b][NE];
      float m = l[0];
      for (int e = 1; e <= NE; ++e) m = fmaxf(m, l[e]);
      float z = 0.f, p[NE + 1];
      for (int e = 0; e <= NE; ++e) { p[e] = __expf(l[e] - m); z += p[e]; }
      float zi = 1.f / z, ent = 0.f;
      for (int e = 0; e <= NE; ++e) {
        float pp = p[e] * zi;
        ent -= pp * __logf(pp + 1e-9f);
      }
      if (aprev[b]) entsum += ent;
      int ch = 0; float bm = l[0];
      for (int e = 1; e <= NE; ++e) if (l[e] > bm) { bm = l[e]; ch = e; }
      int g = (aprev[b] && ch < NE) ? 1 : 0;
      int ix = g ? ch : 0;
      visits[b * NE + ix] += g;
      idx[b] = ix; go[b] = g; active[b] = g;
    }
    if (cnt > 0) *ent_total += entsum / (float)cnt;
  }
}

// ---------------- bf16 MFMA expert GEMM: O[b] = X[b] @ W[idx[b]].T + bias[idx[b]] ----------------
// Inactive batches: zero-fill the full O tile (keeps every ws byte written-this-call;
// downstream values for inactive b are discarded by the gated rep-select).
template <int RELU>
__global__ __launch_bounds__(256) void k_gemm_bf16(
    const float* __restrict__ Xall, int sx,
    const float* __restrict__ Wall, const float* __restrict__ ball,
    float* __restrict__ Oall, int so, int N, int K,
    const int* __restrict__ go, const int* __restrict__ idx) {
  int b = blockIdx.z;
  float* O = Oall + (size_t)b * so;
  int t = threadIdx.x;
  int lane = t & 63, wave = t >> 6;
  int wm = (wave >> 1) * 64, wn = (wave & 1) * 64;
  int bm = blockIdx.x * 128, bn = blockIdx.y * 128;
  int lrow = (lane >> 4) * 4, lcol = lane & 15;
  if (!go[b]) {
#pragma unroll
    for (int nf = 0; nf < 4; ++nf) {
      int col = bn + wn + nf * 16 + lcol;
#pragma unroll
      for (int mf = 0; mf < 4; ++mf)
#pragma unroll
        for (int r = 0; r < 4; ++r)
          O[(size_t)(bm + wm + mf * 16 + lrow + r) * N + col] = 0.f;
    }
    return;
  }
  const float* A = Xall + (size_t)b * sx;
  const float* W = Wall + (size_t)idx[b] * N * K;
  const float* bias = ball + (size_t)idx[b] * N;

  __shared__ __align__(16) unsigned short As[128][48];
  __shared__ __align__(16) unsigned short Bs[128][48];
  f32x4 acc[4][4];
#pragma unroll
  for (int i = 0; i < 4; ++i)
#pragma unroll
    for (int j = 0; j < 4; ++j) acc[i][j] = (f32x4){0.f, 0.f, 0.f, 0.f};

  for (int k0 = 0; k0 < K; k0 += 32) {
    __syncthreads();
#pragma unroll
    for (int u = 0; u < 4; ++u) {
      int f = t + u * 256;
      int r = f >> 3, c = (f & 7) * 4;
      float4 av = *(const float4*)&A[(size_t)(bm + r) * K + k0 + c];
      As[r][c + 0] = f2bf(av.x); As[r][c + 1] = f2bf(av.y);
      As[r][c + 2] = f2bf(av.z); As[r][c + 3] = f2bf(av.w);
      float4 wv = *(const float4*)&W[(size_t)(bn + r) * K + k0 + c];
      Bs[r][c + 0] = f2bf(wv.x); Bs[r][c + 1] = f2bf(wv.y);
      Bs[r][c + 2] = f2bf(wv.z); Bs[r][c + 3] = f2bf(wv.w);
    }
    __syncthreads();
    short8 a[4], bfr[4];
    int row0 = (lane & 15), kof = (lane >> 4) * 8;
#pragma unroll
    for (int mf = 0; mf < 4; ++mf)
      a[mf] = *(const short8*)&As[wm + mf * 16 + row0][kof];
#pragma unroll
    for (int nf = 0; nf < 4; ++nf)
      bfr[nf] = *(const short8*)&Bs[wn + nf * 16 + row0][kof];
#pragma unroll
    for (int mf = 0; mf < 4; ++mf)
#pragma unroll
      for (int nf = 0; nf < 4; ++nf)
        acc[mf][nf] = __builtin_amdgcn_mfma_f32_16x16x32_bf16(a[mf], bfr[nf], acc[mf][nf], 0, 0, 0);
  }
#pragma unroll
  for (int nf = 0; nf < 4; ++nf) {
    int col = bn + wn + nf * 16 + lcol;
    float bv = bias[col];
#pragma unroll
    for (int mf = 0; mf < 4; ++mf) {
#pragma unroll
      for (int r = 0; r < 4; ++r) {
        int row = bm + wm + mf * 16 + lrow + r;
        float v = acc[mf][nf][r] + bv;
        if (RELU) v = fmaxf(v, 0.f);
        O[(size_t)row * N + col] = v;
      }
    }
  }
}

// ---------------- attention: one block per (i, h, b); zero-fill inactive ----------------
__global__ __launch_bounds__(256) void k_attn(const float* __restrict__ qkv,
                                              float* __restrict__ ctx,
                                              const int* __restrict__ go) {
  int b = blockIdx.z;
  int h = blockIdx.y, i = blockIdx.x;
  int t = threadIdx.x;
  if (!go[b]) {
    if (t < 64) ctx[((size_t)b * NS + i) * ND + h * NDH + t] = 0.f;
    return;
  }
  const float* qb = qkv + ((size_t)b * NS) * (3 * ND);
  __shared__ float q[NDH];
  __shared__ float p[NS];
  __shared__ float red[256];
  if (t < NDH) q[t] = qb[(size_t)i * (3 * ND) + h * NDH + t];
  __syncthreads();
  const float* kr = qb + ND + h * NDH + (size_t)t * (3 * ND);
  float s = 0.f;
#pragma unroll
  for (int d = 0; d < NDH; d += 4) {
    float4 kv = *(const float4*)&kr[d];
    s += q[d] * kv.x + q[d + 1] * kv.y + q[d + 2] * kv.z + q[d + 3] * kv.w;
  }
  s *= 0.125f;  // 1/sqrt(64)
  red[t] = s; __syncthreads();
  for (int off = 128; off > 0; off >>= 1) {
    if (t < off) red[t] = fmaxf(red[t], red[t + off]);
    __syncthreads();
  }
  float m = red[0];
  __syncthreads();
  float e = __expf(s - m);
  p[t] = e; red[t] = e; __syncthreads();
  for (int off = 128; off > 0; off >>= 1) {
    if (t < off) red[t] += red[t + off];
    __syncthreads();
  }
  float zinv = 1.f / red[0];
  __syncthreads();
  int g4 = t >> 6, d = t & 63;
  const float* vr = qb + 2 * ND + h * NDH + d + (size_t)(g4 * 64) * (3 * ND);
  float acc = 0.f;
#pragma unroll 8
  for (int j = 0; j < 64; ++j) acc += p[g4 * 64 + j] * vr[(size_t)j * (3 * ND)];
  red[t] = acc; __syncthreads();
  if (t < 64) {
    float r = (red[t] + red[t + 64] + red[t + 128] + red[t + 192]) * zinv;
    ctx[((size_t)b * NS + i) * ND + h * NDH + t] = r;
  }
}

// ---------------- residual + LayerNorm (+optional tag); GATED selects rep-update ----------------
template <int GATED>
__global__ __launch_bounds__(256) void k_ln(const float* __restrict__ xin,
                                            const float* __restrict__ yin,
                                            const float* __restrict__ gall,
                                            const float* __restrict__ ball,
                                            const float* __restrict__ tagall,
                                            float* __restrict__ out,
                                            const int* __restrict__ go,
                                            const int* __restrict__ idx) {
  int b = blockIdx.y;
  // GATED (rep update): inactive batches keep rep as-is — rep is fully written by
  // k_embed every call, so skipping the write leaves current-call data, exactly
  // the reference's where(go, new, old).
  if (GATED && !go[b]) return;
  int s = blockIdx.x;
  size_t base = ((size_t)b * NS + s) * ND;
  int t = threadIdx.x;
  float v0 = xin[base + t] + yin[base + t];
  float v1 = xin[base + t + 256] + yin[base + t + 256];
  __shared__ float red[256];
  red[t] = v0 + v1; __syncthreads();
  for (int off = 128; off > 0; off >>= 1) {
    if (t < off) red[t] += red[t + off];
    __syncthreads();
  }
  float mu = red[0] * (1.f / ND);
  __syncthreads();
  float d0 = v0 - mu, d1 = v1 - mu;
  red[t] = d0 * d0 + d1 * d1; __syncthreads();
  for (int off = 128; off > 0; off >>= 1) {
    if (t < off) red[t] += red[t + off];
    __syncthreads();
  }
  float rs = rsqrtf(red[0] * (1.f / ND) + 1e-5f);
  int ix = idx[b];
  const float* g = gall + ix * ND;
  const float* bb = ball + ix * ND;
  float t0 = 0.f, t1 = 0.f;
  if (tagall) { t0 = tagall[ix * ND + t]; t1 = tagall[ix * ND + t + 256]; }
  out[base + t] = d0 * rs * g[t] + bb[t] + t0;
  out[base + t + 256] = d1 * rs * g[t + 256] + bb[t + 256] + t1;
}

// ---------------- fp32 -> bf16 cast, 8 elems/thread ----------------
__global__ __launch_bounds__(256) void k_cast(const float* __restrict__ src,
                                              unsigned short* __restrict__ dst, int n8) {
  int i = blockIdx.x * 256 + threadIdx.x;
  if (i >= n8) return;
  const float4* s4 = (const float4*)src;
  float4 a = s4[i * 2], b = s4[i * 2 + 1];
  short8 v;
  v[0] = (short)f2bf(a.x); v[1] = (short)f2bf(a.y);
  v[2] = (short)f2bf(a.z); v[3] = (short)f2bf(a.w);
  v[4] = (short)f2bf(b.x); v[5] = (short)f2bf(b.y);
  v[6] = (short)f2bf(b.z); v[7] = (short)f2bf(b.w);
  *(short8*)&dst[(size_t)i * 8] = v;
}

// ---------------- LM head: bf16-input MFMA GEMM ----------------
__global__ __launch_bounds__(256) void k_lmhead_bf16(const unsigned short* __restrict__ Ab,
                                                     const unsigned short* __restrict__ Wb,
                                                     const float* __restrict__ bias,
                                                     float* __restrict__ out) {
  __shared__ __align__(16) unsigned short As[128][40];
  __shared__ __align__(16) unsigned short Bs[128][40];
  int t = threadIdx.x;
  int lane = t & 63, wave = t >> 6;
  int wm = (wave >> 1) * 64, wn = (wave & 1) * 64;
  int bm = blockIdx.x * 128, bn = blockIdx.y * 128;
  f32x4 acc[4][4];
#pragma unroll
  for (int i = 0; i < 4; ++i)
#pragma unroll
    for (int j = 0; j < 4; ++j) acc[i][j] = (f32x4){0.f, 0.f, 0.f, 0.f};

  for (int k0 = 0; k0 < ND; k0 += 32) {
    __syncthreads();
#pragma unroll
    for (int u = 0; u < 2; ++u) {
      int f = t + u * 256;
      int r = f >> 2, c = (f & 3) * 8;
      *(short8*)&As[r][c] = *(const short8*)&Ab[(size_t)(bm + r) * ND + k0 + c];
      *(short8*)&Bs[r][c] = *(const short8*)&Wb[(size_t)(bn + r) * ND + k0 + c];
    }
    __syncthreads();
    short8 a[4], bfr[4];
    int row0 = (lane & 15), kof = (lane >> 4) * 8;
#pragma unroll
    for (int mf = 0; mf < 4; ++mf)
      a[mf] = *(const short8*)&As[wm + mf * 16 + row0][kof];
#pragma unroll
    for (int nf = 0; nf < 4; ++nf)
      bfr[nf] = *(const short8*)&Bs[wn + nf * 16 + row0][kof];
#pragma unroll
    for (int mf = 0; mf < 4; ++mf)
#pragma unroll
      for (int nf = 0; nf < 4; ++nf)
        acc[mf][nf] = __builtin_amdgcn_mfma_f32_16x16x32_bf16(a[mf], bfr[nf], acc[mf][nf], 0, 0, 0);
  }
  int lrow = (lane >> 4) * 4, lcol = lane & 15;
#pragma unroll
  for (int nf = 0; nf < 4; ++nf) {
    int col = bn + wn + nf * 16 + lcol;
    float bv = bias[col];
#pragma unroll
    for (int mf = 0; mf < 4; ++mf) {
#pragma unroll
      for (int r = 0; r < 4; ++r) {
        int row = bm + wm + mf * 16 + lrow + r;
        out[(size_t)row * NV + col] = acc[mf][nf][r] + bv;
      }
    }
  }
}

__global__ void k_ent(const float* __restrict__ entp, float* __restrict__ dst) {
  *dst = *entp;
}

extern "C" void kernel_launch(void* const* d_in, const int* in_sizes, int n_in,
                              void* d_out, int out_size, void* d_ws, size_t ws_size,
                              hipStream_t stream) {
  const int* ids   = (const int*)d_in[0];
  const float* emb = (const float*)d_in[1];
  const float* pe  = (const float*)d_in[2];
  const float* Wqkv = (const float*)d_in[3];
  const float* bqkv = (const float*)d_in[4];
  const float* Wo   = (const float*)d_in[5];
  const float* bo   = (const float*)d_in[6];
  const float* W1   = (const float*)d_in[7];
  const float* b1   = (const float*)d_in[8];
  const float* W2   = (const float*)d_in[9];
  const float* b2   = (const float*)d_in[10];
  const float* g1   = (const float*)d_in[11];
  const float* be1  = (const float*)d_in[12];
  const float* g2   = (const float*)d_in[13];
  const float* be2  = (const float*)d_in[14];
  const float* tag  = (const float*)d_in[15];
  const float* rw1  = (const float*)d_in[16];
  const float* rb1  = (const float*)d_in[17];
  const float* rw2  = (const float*)d_in[18];
  const float* rb2  = (const float*)d_in[19];
  const float* lmw  = (const float*)d_in[20];
  const float* lmb  = (const float*)d_in[21];
  float* out = (float*)d_out;

  float* ws = (float*)d_ws;
  size_t o = 0;
  float* rep = ws + o;  o += (size_t)NB * NS * ND;       // 1,048,576 f
  float* x1  = ws + o;  o += (size_t)NB * NS * ND;       // 1,048,576 f
  float* qkv = ws + o;  o += (size_t)NB * NS * 3 * ND;   // 3,145,728 f
  float* ctx = ws + o;  o += (size_t)NB * NS * ND;       // 1,048,576 f
  float* hid = ws + o;  o += (size_t)NB * NS * NFF;      // 4,194,304 f
  float* tmp = ws + o;  o += (size_t)NB * NS * ND;       // 1,048,576 f
  float* summ = ws + o; o += NB * ND;
  int* visits = (int*)(ws + o);
  int* active = visits + NB * NE;
  int* idx = active + NB;
  int* go = idx + NB;
  float* entp = (float*)(go + NB);

  // After the step loop qkv/ctx/hid and tmp are dead: reuse for bf16 LM-head inputs.
  // Wb needs 16.384M ushort = 8.192M floats <= qkv+ctx+hid span (8.388M floats).
  unsigned short* Wb = (unsigned short*)qkv;
  unsigned short* Ab = (unsigned short*)tmp;  // 1.048M ushort <= tmp (1.048M floats)

  k_init<<<1, 64, 0, stream>>>(visits, active, entp);
  k_embed<<<NB * NS, 256, 0, stream>>>(ids, emb, pe, rep);

  for (int step = 0; step < 4; ++step) {
    k_summary<<<NB * 2, 256, 0, stream>>>(rep, summ);
    k_router<<<1, 256, 0, stream>>>(summ, rw1, rb1, rw2, rb2,
                                    visits, active, idx, go, entp);
    // qkv = rep @ Wqkv^T + bqkv   [256 x 1536, K=512]
    k_gemm_bf16<0><<<dim3(2, 12, NB), 256, 0, stream>>>(
        rep, NS * ND, Wqkv, bqkv, qkv, NS * 3 * ND, 3 * ND, ND, go, idx);
    // attention
    k_attn<<<dim3(NS, NH, NB), 256, 0, stream>>>(qkv, ctx, go);
    // attn_out = ctx @ Wo^T + bo   [256 x 512, K=512]
    k_gemm_bf16<0><<<dim3(2, 4, NB), 256, 0, stream>>>(
        ctx, NS * ND, Wo, bo, tmp, NS * ND, ND, ND, go, idx);
    // x1 = LN(rep + attn_out)  (always computed; inactive b discarded downstream)
    k_ln<0><<<dim3(NS, NB), 256, 0, stream>>>(rep, tmp, g1, be1, nullptr, x1, go, idx);
    // hid = relu(x1 @ W1^T + b1)   [256 x 2048, K=512]
    k_gemm_bf16<1><<<dim3(2, 16, NB), 256, 0, stream>>>(
        x1, NS * ND, W1, b1, hid, NS * NFF, NFF, ND, go, idx);
    // ff = hid @ W2^T + b2   [256 x 512, K=2048]
    k_gemm_bf16<0><<<dim3(2, 4, NB), 256, 0, stream>>>(
        hid, NS * NFF, W2, b2, tmp, NS * ND, ND, NFF, go, idx);
    // rep = LN(x1 + ff) + tag   (gated select)
    k_ln<1><<<dim3(NS, NB), 256, 0, stream>>>(x1, tmp, g2, be2, tag, rep, go, idx);
  }

  // Pre-cast LM-head inputs to bf16.
  k_cast<<<(NV * ND / 8 + 255) / 256, 256, 0, stream>>>(lmw, Wb, NV * ND / 8);
  k_cast<<<(NB * NS * ND / 8 + 255) / 256, 256, 0, stream>>>(rep, Ab, NB * NS * ND / 8);

  k_lmhead_bf16<<<dim3(2048 / 128, NV / 128), 256, 0, stream>>>(Ab, Wb, lmb, out);
  k_ent<<<1, 1, 0, stream>>>(entp, out + (size_t)NB * NS * NV);
}

// Round 4
// 1076.879 us; speedup vs baseline: 1.7474x; 1.4668x over previous
//
#include <hip/hip_runtime.h>
#include <hip/hip_bf16.h>

#define NB 8
#define NS 256
#define ND 512
#define NH 8
#define NDH 64
#define NFF 2048
#define NE 8
#define NV 32000
#define NRH 256
#define MAXV 2
#define NEGV (-1e9f)

typedef __attribute__((ext_vector_type(8))) short short8;
typedef __attribute__((ext_vector_type(4))) float f32x4;

__device__ __forceinline__ unsigned short f2bf(float x) {
  unsigned int u = __float_as_uint(x);
  u = (u + 0x7fffu + ((u >> 16) & 1u)) >> 16;
  return (unsigned short)u;
}

// ---------------- state init ----------------
__global__ void k_init(int* visits, int* active, float* ent) {
  int t = threadIdx.x;
  if (t < NB * NE) visits[t] = 0;
  if (t < NB) active[t] = 1;
  if (t == 0) *ent = 0.f;
}

// ---------------- embedding ----------------
__global__ __launch_bounds__(256) void k_embed(const int* __restrict__ ids,
                                               const float* __restrict__ emb,
                                               const float* __restrict__ pe,
                                               float* __restrict__ rep) {
  int bs = blockIdx.x;               // b*NS + s
  int s = bs & (NS - 1);
  int id = ids[bs];
  const float sc = (id != 0) ? 22.627416997969522f : 0.f;  // sqrt(512), pad row zeroed
  const float* er = emb + (size_t)id * ND;
  const float* per = pe + (size_t)s * ND;
  float* out = rep + (size_t)bs * ND;
  for (int d = threadIdx.x; d < ND; d += 256)
    out[d] = er[d] * sc + per[d];
}

// ---------------- summary = rep.mean(1): grid (ND/64, NB) ----------------
__global__ __launch_bounds__(256) void k_summary(const float* __restrict__ rep,
                                                 float* __restrict__ summ) {
  int b = blockIdx.y;
  int t = threadIdx.x;
  int d = blockIdx.x * 64 + (t & 63);
  int sq = t >> 6;  // s-quarter 0..3
  const float* r = rep + ((size_t)b * NS + sq * 64) * ND + d;
  float acc = 0.f;
  for (int s = 0; s < 64; ++s) acc += r[(size_t)s * ND];
  __shared__ float red[4][64];
  red[sq][t & 63] = acc;
  __syncthreads();
  if (t < 64)
    summ[b * ND + blockIdx.x * 64 + t] =
        (red[0][t] + red[1][t] + red[2][t] + red[3][t]) * (1.f / NS);
}

// ---------------- router (1 block) ----------------
__global__ __launch_bounds__(256) void k_router(const float* __restrict__ summ,
                                                const float* __restrict__ rw1,
                                                const float* __restrict__ rb1,
                                                const float* __restrict__ rw2,
                                                const float* __restrict__ rb2,
                                                int* visits, int* active,
                                                int* idx, int* go, float* ent_total) {
  __shared__ float sm[NB][ND];
  __shared__ float h[NB][NRH];
  __shared__ float lg[NB][NE + 1];
  int t = threadIdx.x;
  for (int i = t; i < NB * ND; i += 256) sm[i >> 9][i & 511] = summ[i];
  __syncthreads();
  {
    const float* w = rw1 + (size_t)t * ND;
    float acc[NB];
#pragma unroll
    for (int b = 0; b < NB; ++b) acc[b] = rb1[t];
    for (int d = 0; d < ND; ++d) {
      float wv = w[d];
#pragma unroll
      for (int b = 0; b < NB; ++b) acc[b] += sm[b][d] * wv;
    }
#pragma unroll
    for (int b = 0; b < NB; ++b) h[b][t] = fmaxf(acc[b], 0.f);
  }
  __syncthreads();
  if (t < NB * (NE + 1)) {
    int b = t / (NE + 1), e = t % (NE + 1);
    const float* w = rw2 + e * NRH;
    float a = rb2[e];
    for (int r = 0; r < NRH; ++r) a += h[b][r] * w[r];
    lg[b][e] = a;
  }
  __syncthreads();
  if (t == 0) {
    int aprev[NB];
    int cnt = 0;
    for (int b = 0; b < NB; ++b) { aprev[b] = active[b]; cnt += aprev[b]; }
    float entsum = 0.f;
    for (int b = 0; b < NB; ++b) {
      float l[NE + 1];
      for (int e = 0; e < NE; ++e)
        l[e] = (visits[b * NE + e] >= MAXV) ? NEGV : lg[b][e];
      l[NE] = lg[b][NE];
      float m = l[0];
      for (int e = 1; e <= NE; ++e) m = fmaxf(m, l[e]);
      float z = 0.f, p[NE + 1];
      for (int e = 0; e <= NE; ++e) { p[e] = __expf(l[e] - m); z += p[e]; }
      float zi = 1.f / z, ent = 0.f;
      for (int e = 0; e <= NE; ++e) {
        float pp = p[e] * zi;
        ent -= pp * __logf(pp + 1e-9f);
      }
      if (aprev[b]) entsum += ent;
      int ch = 0; float bm = l[0];
      for (int e = 1; e <= NE; ++e) if (l[e] > bm) { bm = l[e]; ch = e; }
      int g = (aprev[b] && ch < NE) ? 1 : 0;
      int ix = g ? ch : 0;
      visits[b * NE + ix] += g;
      idx[b] = ix; go[b] = g; active[b] = g;
    }
    if (cnt > 0) *ent_total += entsum / (float)cnt;
  }
}

// ---------------- bf16 MFMA expert GEMM: O[b] = X[b] @ W[idx[b]].T + bias[idx[b]] ----------------
template <int RELU>
__global__ __launch_bounds__(256) void k_gemm_bf16(
    const float* __restrict__ Xall, int sx,
    const float* __restrict__ Wall, const float* __restrict__ ball,
    float* __restrict__ Oall, int so, int N, int K,
    const int* __restrict__ go, const int* __restrict__ idx) {
  int b = blockIdx.z;
  float* O = Oall + (size_t)b * so;
  int t = threadIdx.x;
  int lane = t & 63, wave = t >> 6;
  int wm = (wave >> 1) * 64, wn = (wave & 1) * 64;
  int bm = blockIdx.x * 128, bn = blockIdx.y * 128;
  int lrow = (lane >> 4) * 4, lcol = lane & 15;
  if (!go[b]) {
#pragma unroll
    for (int nf = 0; nf < 4; ++nf) {
      int col = bn + wn + nf * 16 + lcol;
#pragma unroll
      for (int mf = 0; mf < 4; ++mf)
#pragma unroll
        for (int r = 0; r < 4; ++r)
          O[(size_t)(bm + wm + mf * 16 + lrow + r) * N + col] = 0.f;
    }
    return;
  }
  const float* A = Xall + (size_t)b * sx;
  const float* W = Wall + (size_t)idx[b] * N * K;
  const float* bias = ball + (size_t)idx[b] * N;

  __shared__ __align__(16) unsigned short As[128][48];
  __shared__ __align__(16) unsigned short Bs[128][48];
  f32x4 acc[4][4];
#pragma unroll
  for (int i = 0; i < 4; ++i)
#pragma unroll
    for (int j = 0; j < 4; ++j) acc[i][j] = (f32x4){0.f, 0.f, 0.f, 0.f};

  for (int k0 = 0; k0 < K; k0 += 32) {
    __syncthreads();
#pragma unroll
    for (int u = 0; u < 4; ++u) {
      int f = t + u * 256;
      int r = f >> 3, c = (f & 7) * 4;
      float4 av = *(const float4*)&A[(size_t)(bm + r) * K + k0 + c];
      As[r][c + 0] = f2bf(av.x); As[r][c + 1] = f2bf(av.y);
      As[r][c + 2] = f2bf(av.z); As[r][c + 3] = f2bf(av.w);
      float4 wv = *(const float4*)&W[(size_t)(bn + r) * K + k0 + c];
      Bs[r][c + 0] = f2bf(wv.x); Bs[r][c + 1] = f2bf(wv.y);
      Bs[r][c + 2] = f2bf(wv.z); Bs[r][c + 3] = f2bf(wv.w);
    }
    __syncthreads();
    short8 a[4], bfr[4];
    int row0 = (lane & 15), kof = (lane >> 4) * 8;
#pragma unroll
    for (int mf = 0; mf < 4; ++mf)
      a[mf] = *(const short8*)&As[wm + mf * 16 + row0][kof];
#pragma unroll
    for (int nf = 0; nf < 4; ++nf)
      bfr[nf] = *(const short8*)&Bs[wn + nf * 16 + row0][kof];
#pragma unroll
    for (int mf = 0; mf < 4; ++mf)
#pragma unroll
      for (int nf = 0; nf < 4; ++nf)
        acc[mf][nf] = __builtin_amdgcn_mfma_f32_16x16x32_bf16(a[mf], bfr[nf], acc[mf][nf], 0, 0, 0);
  }
#pragma unroll
  for (int nf = 0; nf < 4; ++nf) {
    int col = bn + wn + nf * 16 + lcol;
    float bv = bias[col];
#pragma unroll
    for (int mf = 0; mf < 4; ++mf) {
#pragma unroll
      for (int r = 0; r < 4; ++r) {
        int row = bm + wm + mf * 16 + lrow + r;
        float v = acc[mf][nf][r] + bv;
        if (RELU) v = fmaxf(v, 0.f);
        O[(size_t)row * N + col] = v;
      }
    }
  }
}

// ---------------- MFMA flash attention: block per (qtile, h, b) ----------------
// Swapped QK^T (mfma(K,Q)) -> per-lane row softmax -> P bf16 in LDS -> PV.
// LDS: lds0 = K (256 x 64 bf16, XOR-swizzled) overlaid later by P (64 x 256);
//      lds1 = V^T (64 x 256 bf16, XOR-swizzled). Total exactly 64 KB.
__global__ __launch_bounds__(256) void k_attn2(const float* __restrict__ qkv,
                                               float* __restrict__ ctx,
                                               const int* __restrict__ go) {
  int b = blockIdx.z, h = blockIdx.y, qt = blockIdx.x;
  int t = threadIdx.x;
  if (!go[b]) {
    int r = t >> 4, c0 = (t & 15) * 4;
    float4 z = {0.f, 0.f, 0.f, 0.f};
#pragma unroll
    for (int i = 0; i < 4; ++i)
      *(float4*)&ctx[((size_t)b * NS + qt * 64 + r + i * 16) * ND + h * NDH + c0] = z;
    return;
  }
  __shared__ __align__(16) unsigned short lds0[16384];  // K then P
  __shared__ __align__(16) unsigned short lds1[16384];  // V^T
  const float* base = qkv + (size_t)b * NS * (3 * ND);
  int lane = t & 63, w = t >> 6, g = lane >> 4, c = lane & 15;

  // ---- stage K: row k (256), 64 d as bf16. idx = k*64 + ((d) ^ ((k&7)<<3))
  {
    int cc = t & 15, r0 = t >> 4;  // cc: d-quad, r0: row within 16
#pragma unroll
    for (int i = 0; i < 16; ++i) {
      int k = i * 16 + r0;
      float4 v = *(const float4*)&base[(size_t)k * (3 * ND) + ND + h * NDH + cc * 4];
      unsigned long long pk = (unsigned long long)f2bf(v.x) |
                              ((unsigned long long)f2bf(v.y) << 16) |
                              ((unsigned long long)f2bf(v.z) << 32) |
                              ((unsigned long long)f2bf(v.w) << 48);
      *(unsigned long long*)&lds0[k * 64 + ((cc * 4) ^ ((k & 7) << 3))] = pk;
    }
  }
  // ---- stage V^T: row d (64), 256 k. idx = d*256 + (k ^ ((d&7)<<3))
  {
    int d = t & 63, kq = t >> 6;
#pragma unroll
    for (int i = 0; i < 64; ++i) {
      int k = i * 4 + kq;
      float v = base[(size_t)k * (3 * ND) + 2 * ND + h * NDH + d];
      lds1[d * 256 + (k ^ ((d & 7) << 3))] = f2bf(v);
    }
  }
  // ---- Q fragments (B-operand): lane holds Q[q0+c][kd*32 + g*8 .. +8]
  short8 qf[2];
  {
    const float* qp = base + (size_t)(qt * 64 + w * 16 + c) * (3 * ND) + h * NDH;
#pragma unroll
    for (int kd = 0; kd < 2; ++kd) {
      float4 a = *(const float4*)&qp[kd * 32 + g * 8];
      float4 b4 = *(const float4*)&qp[kd * 32 + g * 8 + 4];
      short8 q8;
      q8[0] = (short)f2bf(a.x); q8[1] = (short)f2bf(a.y);
      q8[2] = (short)f2bf(a.z); q8[3] = (short)f2bf(a.w);
      q8[4] = (short)f2bf(b4.x); q8[5] = (short)f2bf(b4.y);
      q8[6] = (short)f2bf(b4.z); q8[7] = (short)f2bf(b4.w);
      qf[kd] = q8;
    }
  }
  __syncthreads();

  // ---- S^T = K @ Q^T : acc[mf], key = mf*16 + g*4 + r, q = w*16 + c
  f32x4 sacc[16];
#pragma unroll
  for (int mf = 0; mf < 16; ++mf) sacc[mf] = (f32x4){0.f, 0.f, 0.f, 0.f};
#pragma unroll
  for (int mf = 0; mf < 16; ++mf) {
#pragma unroll
    for (int kd = 0; kd < 2; ++kd) {
      int row = mf * 16 + c;
      short8 kf = *(const short8*)&lds0[row * 64 + ((kd * 32 + g * 8) ^ ((row & 7) << 3))];
      sacc[mf] = __builtin_amdgcn_mfma_f32_16x16x32_bf16(kf, qf[kd], sacc[mf], 0, 0, 0);
    }
  }
  __syncthreads();  // all waves done reading K; lds0 becomes P

  // ---- softmax over 256 keys of this lane's q row
  float mx = -3.4e38f;
#pragma unroll
  for (int mf = 0; mf < 16; ++mf) {
#pragma unroll
    for (int r = 0; r < 4; ++r) {
      sacc[mf][r] *= 0.125f;
      mx = fmaxf(mx, sacc[mf][r]);
    }
  }
  mx = fmaxf(mx, __shfl_xor(mx, 16));
  mx = fmaxf(mx, __shfl_xor(mx, 32));
  float sum = 0.f;
#pragma unroll
  for (int mf = 0; mf < 16; ++mf)
#pragma unroll
    for (int r = 0; r < 4; ++r) {
      float p = __expf(sacc[mf][r] - mx);
      sacc[mf][r] = p;
      sum += p;
    }
  sum += __shfl_xor(sum, 16);
  sum += __shfl_xor(sum, 32);
  float zi = 1.f / sum;

  // ---- write normalized P (bf16) : row q_l = w*16+c, keys mf*16+g*4..+3
  int q_l = w * 16 + c;
#pragma unroll
  for (int mf = 0; mf < 16; ++mf) {
    unsigned long long pk =
        (unsigned long long)f2bf(sacc[mf][0] * zi) |
        ((unsigned long long)f2bf(sacc[mf][1] * zi) << 16) |
        ((unsigned long long)f2bf(sacc[mf][2] * zi) << 32) |
        ((unsigned long long)f2bf(sacc[mf][3] * zi) << 48);
    *(unsigned long long*)&lds0[q_l * 256 + ((mf * 16 + g * 4) ^ ((q_l & 7) << 3))] = pk;
  }

  // ---- ctx = P @ V : A = P rows (wave's 16 q), B = V^T rows (d)
  f32x4 cacc[4];
#pragma unroll
  for (int nf = 0; nf < 4; ++nf) cacc[nf] = (f32x4){0.f, 0.f, 0.f, 0.f};
#pragma unroll
  for (int ks = 0; ks < 8; ++ks) {
    int prow = w * 16 + c;
    short8 pf = *(const short8*)&lds0[prow * 256 + ((ks * 32 + g * 8) ^ ((prow & 7) << 3))];
#pragma unroll
    for (int nf = 0; nf < 4; ++nf) {
      int vrow = nf * 16 + c;
      short8 vf = *(const short8*)&lds1[vrow * 256 + ((ks * 32 + g * 8) ^ ((vrow & 7) << 3))];
      cacc[nf] = __builtin_amdgcn_mfma_f32_16x16x32_bf16(pf, vf, cacc[nf], 0, 0, 0);
    }
  }
  // D layout: d = nf*16 + c, q = qt*64 + w*16 + g*4 + r
#pragma unroll
  for (int nf = 0; nf < 4; ++nf)
#pragma unroll
    for (int r = 0; r < 4; ++r)
      ctx[((size_t)b * NS + qt * 64 + w * 16 + g * 4 + r) * ND + h * NDH + nf * 16 + c] =
          cacc[nf][r];
}

// ---------------- residual + LayerNorm (+optional tag); GATED selects rep-update ----------------
template <int GATED>
__global__ __launch_bounds__(256) void k_ln(const float* __restrict__ xin,
                                            const float* __restrict__ yin,
                                            const float* __restrict__ gall,
                                            const float* __restrict__ ball,
                                            const float* __restrict__ tagall,
                                            float* __restrict__ out,
                                            const int* __restrict__ go,
                                            const int* __restrict__ idx) {
  int b = blockIdx.y;
  if (GATED && !go[b]) return;
  int s = blockIdx.x;
  size_t base = ((size_t)b * NS + s) * ND;
  int t = threadIdx.x;
  float v0 = xin[base + t] + yin[base + t];
  float v1 = xin[base + t + 256] + yin[base + t + 256];
  __shared__ float red[256];
  red[t] = v0 + v1; __syncthreads();
  for (int off = 128; off > 0; off >>= 1) {
    if (t < off) red[t] += red[t + off];
    __syncthreads();
  }
  float mu = red[0] * (1.f / ND);
  __syncthreads();
  float d0 = v0 - mu, d1 = v1 - mu;
  red[t] = d0 * d0 + d1 * d1; __syncthreads();
  for (int off = 128; off > 0; off >>= 1) {
    if (t < off) red[t] += red[t + off];
    __syncthreads();
  }
  float rs = rsqrtf(red[0] * (1.f / ND) + 1e-5f);
  int ix = idx[b];
  const float* g = gall + ix * ND;
  const float* bb = ball + ix * ND;
  float t0 = 0.f, t1 = 0.f;
  if (tagall) { t0 = tagall[ix * ND + t]; t1 = tagall[ix * ND + t + 256]; }
  out[base + t] = d0 * rs * g[t] + bb[t] + t0;
  out[base + t + 256] = d1 * rs * g[t + 256] + bb[t + 256] + t1;
}

// ---------------- fp32 -> bf16 cast, 8 elems/thread ----------------
__global__ __launch_bounds__(256) void k_cast(const float* __restrict__ src,
                                              unsigned short* __restrict__ dst, int n8) {
  int i = blockIdx.x * 256 + threadIdx.x;
  if (i >= n8) return;
  const float4* s4 = (const float4*)src;
  float4 a = s4[i * 2], b = s4[i * 2 + 1];
  short8 v;
  v[0] = (short)f2bf(a.x); v[1] = (short)f2bf(a.y);
  v[2] = (short)f2bf(a.z); v[3] = (short)f2bf(a.w);
  v[4] = (short)f2bf(b.x); v[5] = (short)f2bf(b.y);
  v[6] = (short)f2bf(b.z); v[7] = (short)f2bf(b.w);
  *(short8*)&dst[(size_t)i * 8] = v;
}

// ---------------- LM head: bf16-input MFMA GEMM ----------------
__global__ __launch_bounds__(256) void k_lmhead_bf16(const unsigned short* __restrict__ Ab,
                                                     const unsigned short* __restrict__ Wb,
                                                     const float* __restrict__ bias,
                                                     float* __restrict__ out) {
  __shared__ __align__(16) unsigned short As[128][40];
  __shared__ __align__(16) unsigned short Bs[128][40];
  int t = threadIdx.x;
  int lane = t & 63, wave = t >> 6;
  int wm = (wave >> 1) * 64, wn = (wave & 1) * 64;
  int bm = blockIdx.x * 128, bn = blockIdx.y * 128;
  f32x4 acc[4][4];
#pragma unroll
  for (int i = 0; i < 4; ++i)
#pragma unroll
    for (int j = 0; j < 4; ++j) acc[i][j] = (f32x4){0.f, 0.f, 0.f, 0.f};

  for (int k0 = 0; k0 < ND; k0 += 32) {
    __syncthreads();
#pragma unroll
    for (int u = 0; u < 2; ++u) {
      int f = t + u * 256;
      int r = f >> 2, c = (f & 3) * 8;
      *(short8*)&As[r][c] = *(const short8*)&Ab[(size_t)(bm + r) * ND + k0 + c];
      *(short8*)&Bs[r][c] = *(const short8*)&Wb[(size_t)(bn + r) * ND + k0 + c];
    }
    __syncthreads();
    short8 a[4], bfr[4];
    int row0 = (lane & 15), kof = (lane >> 4) * 8;
#pragma unroll
    for (int mf = 0; mf < 4; ++mf)
      a[mf] = *(const short8*)&As[wm + mf * 16 + row0][kof];
#pragma unroll
    for (int nf = 0; nf < 4; ++nf)
      bfr[nf] = *(const short8*)&Bs[wn + nf * 16 + row0][kof];
#pragma unroll
    for (int mf = 0; mf < 4; ++mf)
#pragma unroll
      for (int nf = 0; nf < 4; ++nf)
        acc[mf][nf] = __builtin_amdgcn_mfma_f32_16x16x32_bf16(a[mf], bfr[nf], acc[mf][nf], 0, 0, 0);
  }
  int lrow = (lane >> 4) * 4, lcol = lane & 15;
#pragma unroll
  for (int nf = 0; nf < 4; ++nf) {
    int col = bn + wn + nf * 16 + lcol;
    float bv = bias[col];
#pragma unroll
    for (int mf = 0; mf < 4; ++mf) {
#pragma unroll
      for (int r = 0; r < 4; ++r) {
        int row = bm + wm + mf * 16 + lrow + r;
        out[(size_t)row * NV + col] = acc[mf][nf][r] + bv;
      }
    }
  }
}

__global__ void k_ent(const float* __restrict__ entp, float* __restrict__ dst) {
  *dst = *entp;
}

extern "C" void kernel_launch(void* const* d_in, const int* in_sizes, int n_in,
                              void* d_out, int out_size, void* d_ws, size_t ws_size,
                              hipStream_t stream) {
  const int* ids   = (const int*)d_in[0];
  const float* emb = (const float*)d_in[1];
  const float* pe  = (const float*)d_in[2];
  const float* Wqkv = (const float*)d_in[3];
  const float* bqkv = (const float*)d_in[4];
  const float* Wo   = (const float*)d_in[5];
  const float* bo   = (const float*)d_in[6];
  const float* W1   = (const float*)d_in[7];
  const float* b1   = (const float*)d_in[8];
  const float* W2   = (const float*)d_in[9];
  const float* b2   = (const float*)d_in[10];
  const float* g1   = (const float*)d_in[11];
  const float* be1  = (const float*)d_in[12];
  const float* g2   = (const float*)d_in[13];
  const float* be2  = (const float*)d_in[14];
  const float* tag  = (const float*)d_in[15];
  const float* rw1  = (const float*)d_in[16];
  const float* rb1  = (const float*)d_in[17];
  const float* rw2  = (const float*)d_in[18];
  const float* rb2  = (const float*)d_in[19];
  const float* lmw  = (const float*)d_in[20];
  const float* lmb  = (const float*)d_in[21];
  float* out = (float*)d_out;

  float* ws = (float*)d_ws;
  size_t o = 0;
  float* rep = ws + o;  o += (size_t)NB * NS * ND;
  float* x1  = ws + o;  o += (size_t)NB * NS * ND;
  float* qkv = ws + o;  o += (size_t)NB * NS * 3 * ND;
  float* ctx = ws + o;  o += (size_t)NB * NS * ND;
  float* hid = ws + o;  o += (size_t)NB * NS * NFF;
  float* tmp = ws + o;  o += (size_t)NB * NS * ND;
  float* summ = ws + o; o += NB * ND;
  int* visits = (int*)(ws + o);
  int* active = visits + NB * NE;
  int* idx = active + NB;
  int* go = idx + NB;
  float* entp = (float*)(go + NB);

  unsigned short* Wb = (unsigned short*)qkv;  // dead after step loop
  unsigned short* Ab = (unsigned short*)tmp;

  k_init<<<1, 64, 0, stream>>>(visits, active, entp);
  k_embed<<<NB * NS, 256, 0, stream>>>(ids, emb, pe, rep);

  for (int step = 0; step < 4; ++step) {
    k_summary<<<dim3(ND / 64, NB), 256, 0, stream>>>(rep, summ);
    k_router<<<1, 256, 0, stream>>>(summ, rw1, rb1, rw2, rb2,
                                    visits, active, idx, go, entp);
    // qkv = rep @ Wqkv^T + bqkv   [256 x 1536, K=512]
    k_gemm_bf16<0><<<dim3(2, 12, NB), 256, 0, stream>>>(
        rep, NS * ND, Wqkv, bqkv, qkv, NS * 3 * ND, 3 * ND, ND, go, idx);
    // attention (MFMA flash)
    k_attn2<<<dim3(4, NH, NB), 256, 0, stream>>>(qkv, ctx, go);
    // attn_out = ctx @ Wo^T + bo   [256 x 512, K=512]
    k_gemm_bf16<0><<<dim3(2, 4, NB), 256, 0, stream>>>(
        ctx, NS * ND, Wo, bo, tmp, NS * ND, ND, ND, go, idx);
    // x1 = LN(rep + attn_out)
    k_ln<0><<<dim3(NS, NB), 256, 0, stream>>>(rep, tmp, g1, be1, nullptr, x1, go, idx);
    // hid = relu(x1 @ W1^T + b1)
    k_gemm_bf16<1><<<dim3(2, 16, NB), 256, 0, stream>>>(
        x1, NS * ND, W1, b1, hid, NS * NFF, NFF, ND, go, idx);
    // ff = hid @ W2^T + b2
    k_gemm_bf16<0><<<dim3(2, 4, NB), 256, 0, stream>>>(
        hid, NS * NFF, W2, b2, tmp, NS * ND, ND, NFF, go, idx);
    // rep = LN(x1 + ff) + tag   (gated select)
    k_ln<1><<<dim3(NS, NB), 256, 0, stream>>>(x1, tmp, g2, be2, tag, rep, go, idx);
  }

  k_cast<<<(NV * ND / 8 + 255) / 256, 256, 0, stream>>>(lmw, Wb, NV * ND / 8);
  k_cast<<<(NB * NS * ND / 8 + 255) / 256, 256, 0, stream>>>(rep, Ab, NB * NS * ND / 8);

  k_lmhead_bf16<<<dim3(2048 / 128, NV / 128), 256, 0, stream>>>(Ab, Wb, lmb, out);
  k_ent<<<1, 1, 0, stream>>>(entp, out + (size_t)NB * NS * NV);
}

// Round 5
// 847.902 us; speedup vs baseline: 2.2193x; 1.2701x over previous
//
#include <hip/hip_runtime.h>
#include <hip/hip_bf16.h>

#define NB 8
#define NS 256
#define ND 512
#define NH 8
#define NDH 64
#define NFF 2048
#define NE 8
#define NV 32000
#define NRH 256
#define MAXV 2
#define NEGV (-1e9f)

typedef __attribute__((ext_vector_type(8))) short short8;
typedef __attribute__((ext_vector_type(4))) float f32x4;

__device__ __forceinline__ unsigned short f2bf(float x) {
  unsigned int u = __float_as_uint(x);
  u = (u + 0x7fffu + ((u >> 16) & 1u)) >> 16;
  return (unsigned short)u;
}

// ---------------- state init ----------------
__global__ void k_init(int* visits, int* active, float* ent) {
  int t = threadIdx.x;
  if (t < NB * NE) visits[t] = 0;
  if (t < NB) active[t] = 1;
  if (t == 0) *ent = 0.f;
}

// ---------------- fp32 -> bf16 cast, 8 elems/thread ----------------
__global__ __launch_bounds__(256) void k_cast(const float* __restrict__ src,
                                              unsigned short* __restrict__ dst, int n8) {
  int i = blockIdx.x * 256 + threadIdx.x;
  if (i >= n8) return;
  const float4* s4 = (const float4*)src;
  float4 a = s4[i * 2], b = s4[i * 2 + 1];
  short8 v;
  v[0] = (short)f2bf(a.x); v[1] = (short)f2bf(a.y);
  v[2] = (short)f2bf(a.z); v[3] = (short)f2bf(a.w);
  v[4] = (short)f2bf(b.x); v[5] = (short)f2bf(b.y);
  v[6] = (short)f2bf(b.z); v[7] = (short)f2bf(b.w);
  *(short8*)&dst[(size_t)i * 8] = v;
}

// ---------------- embedding (fp32 + bf16 mirror), 64 threads/row ----------------
__global__ __launch_bounds__(64) void k_embed(const int* __restrict__ ids,
                                              const float* __restrict__ emb,
                                              const float* __restrict__ pe,
                                              float* __restrict__ rep,
                                              unsigned short* __restrict__ repb) {
  int bs = blockIdx.x;               // b*NS + s
  int s = bs & (NS - 1);
  int id = ids[bs];
  const float sc = (id != 0) ? 22.627416997969522f : 0.f;  // sqrt(512), pad row zeroed
  const float* er = emb + (size_t)id * ND;
  const float* per = pe + (size_t)s * ND;
  float* out = rep + (size_t)bs * ND;
  unsigned short* outb = repb + (size_t)bs * ND;
  int d = threadIdx.x * 8;
  float4 e0 = *(const float4*)&er[d], e1 = *(const float4*)&er[d + 4];
  float4 p0 = *(const float4*)&per[d], p1 = *(const float4*)&per[d + 4];
  float4 o0 = {e0.x * sc + p0.x, e0.y * sc + p0.y, e0.z * sc + p0.z, e0.w * sc + p0.w};
  float4 o1 = {e1.x * sc + p1.x, e1.y * sc + p1.y, e1.z * sc + p1.z, e1.w * sc + p1.w};
  *(float4*)&out[d] = o0;
  *(float4*)&out[d + 4] = o1;
  short8 v;
  v[0] = (short)f2bf(o0.x); v[1] = (short)f2bf(o0.y);
  v[2] = (short)f2bf(o0.z); v[3] = (short)f2bf(o0.w);
  v[4] = (short)f2bf(o1.x); v[5] = (short)f2bf(o1.y);
  v[6] = (short)f2bf(o1.z); v[7] = (short)f2bf(o1.w);
  *(short8*)&outb[d] = v;
}

// ---------------- summary = rep.mean(1): grid (ND/64, NB) ----------------
__global__ __launch_bounds__(256) void k_summary(const float* __restrict__ rep,
                                                 float* __restrict__ summ) {
  int b = blockIdx.y;
  int t = threadIdx.x;
  int d = blockIdx.x * 64 + (t & 63);
  int sq = t >> 6;
  const float* r = rep + ((size_t)b * NS + sq * 64) * ND + d;
  float acc = 0.f;
  for (int s = 0; s < 64; ++s) acc += r[(size_t)s * ND];
  __shared__ float red[4][64];
  red[sq][t & 63] = acc;
  __syncthreads();
  if (t < 64)
    summ[b * ND + blockIdx.x * 64 + t] =
        (red[0][t] + red[1][t] + red[2][t] + red[3][t]) * (1.f / NS);
}

// ---------------- router (1 block) ----------------
__global__ __launch_bounds__(256) void k_router(const float* __restrict__ summ,
                                                const float* __restrict__ rw1,
                                                const float* __restrict__ rb1,
                                                const float* __restrict__ rw2,
                                                const float* __restrict__ rb2,
                                                int* visits, int* active,
                                                int* idx, int* go, float* ent_total) {
  __shared__ float sm[NB][ND];
  __shared__ float h[NB][NRH];
  __shared__ float lg[NB][NE + 1];
  int t = threadIdx.x;
  for (int i = t; i < NB * ND; i += 256) sm[i >> 9][i & 511] = summ[i];
  __syncthreads();
  {
    const float* w = rw1 + (size_t)t * ND;
    float acc[NB];
#pragma unroll
    for (int b = 0; b < NB; ++b) acc[b] = rb1[t];
    for (int d = 0; d < ND; ++d) {
      float wv = w[d];
#pragma unroll
      for (int b = 0; b < NB; ++b) acc[b] += sm[b][d] * wv;
    }
#pragma unroll
    for (int b = 0; b < NB; ++b) h[b][t] = fmaxf(acc[b], 0.f);
  }
  __syncthreads();
  if (t < NB * (NE + 1)) {
    int b = t / (NE + 1), e = t % (NE + 1);
    const float* w = rw2 + e * NRH;
    float a = rb2[e];
    for (int r = 0; r < NRH; ++r) a += h[b][r] * w[r];
    lg[b][e] = a;
  }
  __syncthreads();
  if (t == 0) {
    int aprev[NB];
    int cnt = 0;
    for (int b = 0; b < NB; ++b) { aprev[b] = active[b]; cnt += aprev[b]; }
    float entsum = 0.f;
    for (int b = 0; b < NB; ++b) {
      float l[NE + 1];
      for (int e = 0; e < NE; ++e)
        l[e] = (visits[b * NE + e] >= MAXV) ? NEGV : lg[b][e];
      l[NE] = lg[b][NE];
      float m = l[0];
      for (int e = 1; e <= NE; ++e) m = fmaxf(m, l[e]);
      float z = 0.f, p[NE + 1];
      for (int e = 0; e <= NE; ++e) { p[e] = __expf(l[e] - m); z += p[e]; }
      float zi = 1.f / z, ent = 0.f;
      for (int e = 0; e <= NE; ++e) {
        float pp = p[e] * zi;
        ent -= pp * __logf(pp + 1e-9f);
      }
      if (aprev[b]) entsum += ent;
      int ch = 0; float bm = l[0];
      for (int e = 1; e <= NE; ++e) if (l[e] > bm) { bm = l[e]; ch = e; }
      int g = (aprev[b] && ch < NE) ? 1 : 0;
      int ix = g ? ch : 0;
      visits[b * NE + ix] += g;
      idx[b] = ix; go[b] = g; active[b] = g;
    }
    if (cnt > 0) *ent_total += entsum / (float)cnt;
  }
}

// ---------------- pure-bf16 MFMA expert GEMM ----------------
// OUT: 0 = fp32 (Fall), 1 = bf16 (Uall), 2 = qkv-split (Qb/Kb/Vt, V transposed)
// ZFILL: zero-fill fp32 out for inactive b (needed when an ungated consumer reads it)
template <int OUT, int RELU, int ZFILL>
__global__ __launch_bounds__(256) void k_gemm(
    const unsigned short* __restrict__ Aall, int sa,
    const unsigned short* __restrict__ Wall, const float* __restrict__ ball,
    float* __restrict__ Fall, unsigned short* __restrict__ Uall, int so,
    int N, int K,
    unsigned short* __restrict__ Qb, unsigned short* __restrict__ Kb,
    unsigned short* __restrict__ Vt,
    const int* __restrict__ go, const int* __restrict__ idx) {
  int b = blockIdx.z;
  int t = threadIdx.x;
  int lane = t & 63, wave = t >> 6;
  int wm = (wave >> 1) * 64, wn = (wave & 1) * 64;
  int bm = blockIdx.x * 128, bn = blockIdx.y * 128;
  int lrow = (lane >> 4) * 4, lcol = lane & 15;
  if (!go[b]) {
    if (ZFILL) {
      float* O = Fall + (size_t)b * so;
#pragma unroll
      for (int nf = 0; nf < 4; ++nf) {
        int col = bn + wn + nf * 16 + lcol;
#pragma unroll
        for (int mf = 0; mf < 4; ++mf)
#pragma unroll
          for (int r = 0; r < 4; ++r)
            O[(size_t)(bm + wm + mf * 16 + lrow + r) * N + col] = 0.f;
      }
    }
    return;
  }
  const unsigned short* A = Aall + (size_t)b * sa;
  const unsigned short* W = Wall + (size_t)idx[b] * N * K;
  const float* bias = ball + (size_t)idx[b] * N;

  __shared__ __align__(16) unsigned short As[128][40];
  __shared__ __align__(16) unsigned short Bs[128][40];
  f32x4 acc[4][4];
#pragma unroll
  for (int i = 0; i < 4; ++i)
#pragma unroll
    for (int j = 0; j < 4; ++j) acc[i][j] = (f32x4){0.f, 0.f, 0.f, 0.f};

  for (int k0 = 0; k0 < K; k0 += 32) {
    __syncthreads();
#pragma unroll
    for (int u = 0; u < 2; ++u) {
      int f = t + u * 256;
      int r = f >> 2, c = (f & 3) * 8;
      *(short8*)&As[r][c] = *(const short8*)&A[(size_t)(bm + r) * K + k0 + c];
      *(short8*)&Bs[r][c] = *(const short8*)&W[(size_t)(bn + r) * K + k0 + c];
    }
    __syncthreads();
    short8 a[4], bfr[4];
    int row0 = (lane & 15), kof = (lane >> 4) * 8;
#pragma unroll
    for (int mf = 0; mf < 4; ++mf)
      a[mf] = *(const short8*)&As[wm + mf * 16 + row0][kof];
#pragma unroll
    for (int nf = 0; nf < 4; ++nf)
      bfr[nf] = *(const short8*)&Bs[wn + nf * 16 + row0][kof];
#pragma unroll
    for (int mf = 0; mf < 4; ++mf)
#pragma unroll
      for (int nf = 0; nf < 4; ++nf)
        acc[mf][nf] = __builtin_amdgcn_mfma_f32_16x16x32_bf16(a[mf], bfr[nf], acc[mf][nf], 0, 0, 0);
  }

  if (OUT == 2) {
    int seg = bn >> 9;  // 0:Q 1:K 2:V — 128-tile never crosses a 512 boundary
#pragma unroll
    for (int nf = 0; nf < 4; ++nf) {
      int col = bn + wn + nf * 16 + lcol;
      float bv = bias[col];
      if (seg < 2) {
        unsigned short* dst = (seg == 0) ? Qb : Kb;
        int cc = col - seg * 512;
#pragma unroll
        for (int mf = 0; mf < 4; ++mf)
#pragma unroll
          for (int r = 0; r < 4; ++r) {
            int row = bm + wm + mf * 16 + lrow + r;
            dst[((size_t)b * NS + row) * ND + cc] = f2bf(acc[mf][nf][r] + bv);
          }
      } else {
        int dcol = col - 1024;
#pragma unroll
        for (int mf = 0; mf < 4; ++mf) {
          int s0 = bm + wm + mf * 16 + lrow;
          unsigned long long pk =
              (unsigned long long)f2bf(acc[mf][nf][0] + bv) |
              ((unsigned long long)f2bf(acc[mf][nf][1] + bv) << 16) |
              ((unsigned long long)f2bf(acc[mf][nf][2] + bv) << 32) |
              ((unsigned long long)f2bf(acc[mf][nf][3] + bv) << 48);
          *(unsigned long long*)&Vt[((size_t)b * 512 + dcol) * 256 + s0] = pk;
        }
      }
    }
  } else {
#pragma unroll
    for (int nf = 0; nf < 4; ++nf) {
      int col = bn + wn + nf * 16 + lcol;
      float bv = bias[col];
#pragma unroll
      for (int mf = 0; mf < 4; ++mf) {
#pragma unroll
        for (int r = 0; r < 4; ++r) {
          int row = bm + wm + mf * 16 + lrow + r;
          float v = acc[mf][nf][r] + bv;
          if (RELU) v = fmaxf(v, 0.f);
          if (OUT == 0)
            Fall[(size_t)b * so + (size_t)row * N + col] = v;
          else
            Uall[(size_t)b * so + (size_t)row * N + col] = f2bf(v);
        }
      }
    }
  }
}

// ---------------- MFMA flash attention, all-bf16 IO: block per (qtile, h, b) ----------------
__global__ __launch_bounds__(256) void k_attn2(const unsigned short* __restrict__ Qb,
                                               const unsigned short* __restrict__ Kb,
                                               const unsigned short* __restrict__ Vt,
                                               unsigned short* __restrict__ ctxb,
                                               const int* __restrict__ go) {
  int b = blockIdx.z, h = blockIdx.y, qt = blockIdx.x;
  int t = threadIdx.x;
  if (!go[b]) {
    short8 z = (short8){0, 0, 0, 0, 0, 0, 0, 0};
#pragma unroll
    for (int i = 0; i < 2; ++i) {
      int task = i * 256 + t;
      int q = task >> 3, cc = task & 7;
      *(short8*)&ctxb[((size_t)b * NS + qt * 64 + q) * ND + h * NDH + cc * 8] = z;
    }
    return;
  }
  __shared__ __align__(16) unsigned short lds0[16384];  // K then P
  __shared__ __align__(16) unsigned short lds1[16384];  // V^T
  int lane = t & 63, w = t >> 6, g = lane >> 4, c = lane & 15;

  // stage K: rows k=0..255, 64 d; 8 short8 chunks per row, swizzled
#pragma unroll
  for (int i = 0; i < 8; ++i) {
    int task = i * 256 + t;
    int k = task >> 3, cc = task & 7;
    short8 v = *(const short8*)&Kb[((size_t)b * NS + k) * ND + h * NDH + cc * 8];
    *(short8*)&lds0[k * 64 + ((cc * 8) ^ ((k & 7) << 3))] = v;
  }
  // stage V^T: rows d=0..63, 256 k; 32 chunks per row, swizzled
#pragma unroll
  for (int i = 0; i < 8; ++i) {
    int task = i * 256 + t;
    int d = task >> 5, kc = task & 31;
    short8 v = *(const short8*)&Vt[((size_t)b * 512 + h * NDH + d) * 256 + kc * 8];
    *(short8*)&lds1[d * 256 + ((kc * 8) ^ ((d & 7) << 3))] = v;
  }
  // Q fragments straight from global bf16
  short8 qf[2];
  {
    const unsigned short* qp = Qb + ((size_t)b * NS + qt * 64 + w * 16 + c) * ND + h * NDH;
    qf[0] = *(const short8*)&qp[g * 8];
    qf[1] = *(const short8*)&qp[32 + g * 8];
  }
  __syncthreads();

  // S^T = K @ Q^T : key = mf*16 + g*4 + r, q = w*16 + c
  f32x4 sacc[16];
#pragma unroll
  for (int mf = 0; mf < 16; ++mf) sacc[mf] = (f32x4){0.f, 0.f, 0.f, 0.f};
#pragma unroll
  for (int mf = 0; mf < 16; ++mf) {
#pragma unroll
    for (int kd = 0; kd < 2; ++kd) {
      int row = mf * 16 + c;
      short8 kf = *(const short8*)&lds0[row * 64 + ((kd * 32 + g * 8) ^ ((row & 7) << 3))];
      sacc[mf] = __builtin_amdgcn_mfma_f32_16x16x32_bf16(kf, qf[kd], sacc[mf], 0, 0, 0);
    }
  }
  __syncthreads();  // lds0 becomes P

  float mx = -3.4e38f;
#pragma unroll
  for (int mf = 0; mf < 16; ++mf) {
#pragma unroll
    for (int r = 0; r < 4; ++r) {
      sacc[mf][r] *= 0.125f;
      mx = fmaxf(mx, sacc[mf][r]);
    }
  }
  mx = fmaxf(mx, __shfl_xor(mx, 16));
  mx = fmaxf(mx, __shfl_xor(mx, 32));
  float sum = 0.f;
#pragma unroll
  for (int mf = 0; mf < 16; ++mf)
#pragma unroll
    for (int r = 0; r < 4; ++r) {
      float p = __expf(sacc[mf][r] - mx);
      sacc[mf][r] = p;
      sum += p;
    }
  sum += __shfl_xor(sum, 16);
  sum += __shfl_xor(sum, 32);
  float zi = 1.f / sum;

  int q_l = w * 16 + c;
#pragma unroll
  for (int mf = 0; mf < 16; ++mf) {
    unsigned long long pk =
        (unsigned long long)f2bf(sacc[mf][0] * zi) |
        ((unsigned long long)f2bf(sacc[mf][1] * zi) << 16) |
        ((unsigned long long)f2bf(sacc[mf][2] * zi) << 32) |
        ((unsigned long long)f2bf(sacc[mf][3] * zi) << 48);
    *(unsigned long long*)&lds0[q_l * 256 + ((mf * 16 + g * 4) ^ ((q_l & 7) << 3))] = pk;
  }

  f32x4 cacc[4];
#pragma unroll
  for (int nf = 0; nf < 4; ++nf) cacc[nf] = (f32x4){0.f, 0.f, 0.f, 0.f};
#pragma unroll
  for (int ks = 0; ks < 8; ++ks) {
    int prow = w * 16 + c;
    short8 pf = *(const short8*)&lds0[prow * 256 + ((ks * 32 + g * 8) ^ ((prow & 7) << 3))];
#pragma unroll
    for (int nf = 0; nf < 4; ++nf) {
      int vrow = nf * 16 + c;
      short8 vf = *(const short8*)&lds1[vrow * 256 + ((ks * 32 + g * 8) ^ ((vrow & 7) << 3))];
      cacc[nf] = __builtin_amdgcn_mfma_f32_16x16x32_bf16(pf, vf, cacc[nf], 0, 0, 0);
    }
  }
#pragma unroll
  for (int nf = 0; nf < 4; ++nf)
#pragma unroll
    for (int r = 0; r < 4; ++r)
      ctxb[((size_t)b * NS + qt * 64 + w * 16 + g * 4 + r) * ND + h * NDH + nf * 16 + c] =
          f2bf(cacc[nf][r]);
}

// ---------------- residual + LayerNorm, wave-per-row, fp32 out + bf16 mirror ----------------
template <int GATED>
__global__ __launch_bounds__(256) void k_lnw(const float* __restrict__ xin,
                                             const float* __restrict__ yin,
                                             const float* __restrict__ gall,
                                             const float* __restrict__ ball,
                                             const float* __restrict__ tagall,
                                             float* __restrict__ outf,
                                             unsigned short* __restrict__ outb,
                                             const int* __restrict__ go,
                                             const int* __restrict__ idx) {
  int b = blockIdx.y;
  if (GATED && !go[b]) return;
  int w = threadIdx.x >> 6, l = threadIdx.x & 63;
  int s = blockIdx.x * 4 + w;
  size_t base = ((size_t)b * NS + s) * ND;
  int d = l * 8;
  float4 x0 = *(const float4*)&xin[base + d];
  float4 x1 = *(const float4*)&xin[base + d + 4];
  float4 y0 = *(const float4*)&yin[base + d];
  float4 y1 = *(const float4*)&yin[base + d + 4];
  float v[8] = {x0.x + y0.x, x0.y + y0.y, x0.z + y0.z, x0.w + y0.w,
                x1.x + y1.x, x1.y + y1.y, x1.z + y1.z, x1.w + y1.w};
  float sum = 0.f;
#pragma unroll
  for (int j = 0; j < 8; ++j) sum += v[j];
#pragma unroll
  for (int off = 1; off < 64; off <<= 1) sum += __shfl_xor(sum, off);
  float mu = sum * (1.f / ND);
  float var = 0.f;
#pragma unroll
  for (int j = 0; j < 8; ++j) { v[j] -= mu; var += v[j] * v[j]; }
#pragma unroll
  for (int off = 1; off < 64; off <<= 1) var += __shfl_xor(var, off);
  float rs = rsqrtf(var * (1.f / ND) + 1e-5f);
  int ix = idx[b];
  float4 g0 = *(const float4*)&gall[ix * ND + d];
  float4 g1 = *(const float4*)&gall[ix * ND + d + 4];
  float4 b0 = *(const float4*)&ball[ix * ND + d];
  float4 b1 = *(const float4*)&ball[ix * ND + d + 4];
  float gg[8] = {g0.x, g0.y, g0.z, g0.w, g1.x, g1.y, g1.z, g1.w};
  float bb[8] = {b0.x, b0.y, b0.z, b0.w, b1.x, b1.y, b1.z, b1.w};
  float o[8];
#pragma unroll
  for (int j = 0; j < 8; ++j) o[j] = v[j] * rs * gg[j] + bb[j];
  if (tagall) {
    float4 t0 = *(const float4*)&tagall[ix * ND + d];
    float4 t1 = *(const float4*)&tagall[ix * ND + d + 4];
    o[0] += t0.x; o[1] += t0.y; o[2] += t0.z; o[3] += t0.w;
    o[4] += t1.x; o[5] += t1.y; o[6] += t1.z; o[7] += t1.w;
  }
  *(float4*)&outf[base + d] = (float4){o[0], o[1], o[2], o[3]};
  *(float4*)&outf[base + d + 4] = (float4){o[4], o[5], o[6], o[7]};
  short8 ob;
#pragma unroll
  for (int j = 0; j < 8; ++j) ob[j] = (short)f2bf(o[j]);
  *(short8*)&outb[base + d] = ob;
}

// ---------------- LM head: bf16-input MFMA GEMM ----------------
__global__ __launch_bounds__(256) void k_lmhead_bf16(const unsigned short* __restrict__ Ab,
                                                     const unsigned short* __restrict__ Wb,
                                                     const float* __restrict__ bias,
                                                     float* __restrict__ out) {
  __shared__ __align__(16) unsigned short As[128][40];
  __shared__ __align__(16) unsigned short Bs[128][40];
  int t = threadIdx.x;
  int lane = t & 63, wave = t >> 6;
  int wm = (wave >> 1) * 64, wn = (wave & 1) * 64;
  int bm = blockIdx.x * 128, bn = blockIdx.y * 128;
  f32x4 acc[4][4];
#pragma unroll
  for (int i = 0; i < 4; ++i)
#pragma unroll
    for (int j = 0; j < 4; ++j) acc[i][j] = (f32x4){0.f, 0.f, 0.f, 0.f};

  for (int k0 = 0; k0 < ND; k0 += 32) {
    __syncthreads();
#pragma unroll
    for (int u = 0; u < 2; ++u) {
      int f = t + u * 256;
      int r = f >> 2, c = (f & 3) * 8;
      *(short8*)&As[r][c] = *(const short8*)&Ab[(size_t)(bm + r) * ND + k0 + c];
      *(short8*)&Bs[r][c] = *(const short8*)&Wb[(size_t)(bn + r) * ND + k0 + c];
    }
    __syncthreads();
    short8 a[4], bfr[4];
    int row0 = (lane & 15), kof = (lane >> 4) * 8;
#pragma unroll
    for (int mf = 0; mf < 4; ++mf)
      a[mf] = *(const short8*)&As[wm + mf * 16 + row0][kof];
#pragma unroll
    for (int nf = 0; nf < 4; ++nf)
      bfr[nf] = *(const short8*)&Bs[wn + nf * 16 + row0][kof];
#pragma unroll
    for (int mf = 0; mf < 4; ++mf)
#pragma unroll
      for (int nf = 0; nf < 4; ++nf)
        acc[mf][nf] = __builtin_amdgcn_mfma_f32_16x16x32_bf16(a[mf], bfr[nf], acc[mf][nf], 0, 0, 0);
  }
  int lrow = (lane >> 4) * 4, lcol = lane & 15;
#pragma unroll
  for (int nf = 0; nf < 4; ++nf) {
    int col = bn + wn + nf * 16 + lcol;
    float bv = bias[col];
#pragma unroll
    for (int mf = 0; mf < 4; ++mf) {
#pragma unroll
      for (int r = 0; r < 4; ++r) {
        int row = bm + wm + mf * 16 + lrow + r;
        out[(size_t)row * NV + col] = acc[mf][nf][r] + bv;
      }
    }
  }
}

__global__ void k_ent(const float* __restrict__ entp, float* __restrict__ dst) {
  *dst = *entp;
}

extern "C" void kernel_launch(void* const* d_in, const int* in_sizes, int n_in,
                              void* d_out, int out_size, void* d_ws, size_t ws_size,
                              hipStream_t stream) {
  const int* ids   = (const int*)d_in[0];
  const float* emb = (const float*)d_in[1];
  const float* pe  = (const float*)d_in[2];
  const float* Wqkv = (const float*)d_in[3];
  const float* bqkv = (const float*)d_in[4];
  const float* Wo   = (const float*)d_in[5];
  const float* bo   = (const float*)d_in[6];
  const float* W1   = (const float*)d_in[7];
  const float* b1   = (const float*)d_in[8];
  const float* W2   = (const float*)d_in[9];
  const float* b2   = (const float*)d_in[10];
  const float* g1   = (const float*)d_in[11];
  const float* be1  = (const float*)d_in[12];
  const float* g2   = (const float*)d_in[13];
  const float* be2  = (const float*)d_in[14];
  const float* tag  = (const float*)d_in[15];
  const float* rw1  = (const float*)d_in[16];
  const float* rb1  = (const float*)d_in[17];
  const float* rw2  = (const float*)d_in[18];
  const float* rb2  = (const float*)d_in[19];
  const float* lmw  = (const float*)d_in[20];
  const float* lmb  = (const float*)d_in[21];
  float* out = (float*)d_out;

  float* ws = (float*)d_ws;
  size_t o = 0;
  float* rep = ws + o;  o += (size_t)NB * NS * ND;   // fp32
  float* x1  = ws + o;  o += (size_t)NB * NS * ND;
  float* tmp = ws + o;  o += (size_t)NB * NS * ND;
  float* summ = ws + o; o += NB * ND;
  int* visits = (int*)(ws + o); o += 1024;
  int* active = visits + NB * NE;
  int* idx = active + NB;
  int* go = idx + NB;
  float* entp = (float*)(go + NB);

  unsigned short* us = (unsigned short*)(ws + o);
  size_t uo = 0;
  unsigned short* rep_b = us + uo; uo += (size_t)NB * NS * ND;
  unsigned short* x1_b  = us + uo; uo += (size_t)NB * NS * ND;
  unsigned short* ctx_b = us + uo; uo += (size_t)NB * NS * ND;
  unsigned short* Qb    = us + uo; uo += (size_t)NB * NS * ND;
  unsigned short* Kb    = us + uo; uo += (size_t)NB * NS * ND;
  unsigned short* Vt    = us + uo; uo += (size_t)NB * NS * ND;
  unsigned short* hid_b = us + uo; uo += (size_t)NB * NS * NFF;
  unsigned short* Wqkv_b = us + uo; uo += (size_t)NE * 3 * ND * ND;
  unsigned short* Wo_b   = us + uo; uo += (size_t)NE * ND * ND;
  unsigned short* W1_b   = us + uo; uo += (size_t)NE * NFF * ND;
  unsigned short* W2_b   = us + uo; uo += (size_t)NE * ND * NFF;
  unsigned short* lmw_b  = us + uo; uo += (size_t)NV * ND;

  k_init<<<1, 64, 0, stream>>>(visits, active, entp);

  // weight pre-casts (deterministic every call)
  k_cast<<<NE * 3 * ND * ND / 8 / 256, 256, 0, stream>>>(Wqkv, Wqkv_b, NE * 3 * ND * ND / 8);
  k_cast<<<NE * ND * ND / 8 / 256, 256, 0, stream>>>(Wo, Wo_b, NE * ND * ND / 8);
  k_cast<<<NE * NFF * ND / 8 / 256, 256, 0, stream>>>(W1, W1_b, NE * NFF * ND / 8);
  k_cast<<<NE * ND * NFF / 8 / 256, 256, 0, stream>>>(W2, W2_b, NE * ND * NFF / 8);
  k_cast<<<NV * ND / 8 / 256, 256, 0, stream>>>(lmw, lmw_b, NV * ND / 8);

  k_embed<<<NB * NS, 64, 0, stream>>>(ids, emb, pe, rep, rep_b);

  for (int step = 0; step < 4; ++step) {
    k_summary<<<dim3(ND / 64, NB), 256, 0, stream>>>(rep, summ);
    k_router<<<1, 256, 0, stream>>>(summ, rw1, rb1, rw2, rb2,
                                    visits, active, idx, go, entp);
    // qkv: rep_b @ Wqkv^T + bqkv -> Qb/Kb bf16, Vt transposed bf16
    k_gemm<2, 0, 0><<<dim3(2, 12, NB), 256, 0, stream>>>(
        rep_b, NS * ND, Wqkv_b, bqkv, nullptr, nullptr, 0, 3 * ND, ND,
        Qb, Kb, Vt, go, idx);
    // attention (all-bf16 flash)
    k_attn2<<<dim3(4, NH, NB), 256, 0, stream>>>(Qb, Kb, Vt, ctx_b, go);
    // attn_out = ctx @ Wo^T + bo -> tmp fp32 (zero-filled for inactive: ln1 is ungated)
    k_gemm<0, 0, 1><<<dim3(2, 4, NB), 256, 0, stream>>>(
        ctx_b, NS * ND, Wo_b, bo, tmp, nullptr, NS * ND, ND, ND,
        nullptr, nullptr, nullptr, go, idx);
    // x1 = LN(rep + attn_out), fp32 + bf16 mirror (always)
    k_lnw<0><<<dim3(NS / 4, NB), 256, 0, stream>>>(rep, tmp, g1, be1, nullptr,
                                                   x1, x1_b, go, idx);
    // hid = relu(x1 @ W1^T + b1) -> bf16 only
    k_gemm<1, 1, 0><<<dim3(2, 16, NB), 256, 0, stream>>>(
        x1_b, NS * ND, W1_b, b1, nullptr, hid_b, NS * NFF, NFF, ND,
        nullptr, nullptr, nullptr, go, idx);
    // ff = hid @ W2^T + b2 -> tmp fp32 (inactive: not read by gated ln2)
    k_gemm<0, 0, 0><<<dim3(2, 4, NB), 256, 0, stream>>>(
        hid_b, NS * NFF, W2_b, b2, tmp, nullptr, NS * ND, ND, NFF,
        nullptr, nullptr, nullptr, go, idx);
    // rep = LN(x1 + ff) + tag (gated select), fp32 + bf16 mirror
    k_lnw<1><<<dim3(NS / 4, NB), 256, 0, stream>>>(x1, tmp, g2, be2, tag,
                                                   rep, rep_b, go, idx);
  }

  k_lmhead_bf16<<<dim3(2048 / 128, NV / 128), 256, 0, stream>>>(rep_b, lmw_b, lmb, out);
  k_ent<<<1, 1, 0, stream>>>(entp, out + (size_t)NB * NS * NV);
}

// Round 6
// 826.745 us; speedup vs baseline: 2.2761x; 1.0256x over previous
//
#include <hip/hip_runtime.h>
#include <hip/hip_bf16.h>

#define NB 8
#define NS 256
#define ND 512
#define NH 8
#define NDH 64
#define NFF 2048
#define NE 8
#define NV 32000
#define NRH 256
#define MAXV 2
#define NEGV (-1e9f)

typedef __attribute__((ext_vector_type(8))) short short8;
typedef __attribute__((ext_vector_type(4))) float f32x4;

__device__ __forceinline__ unsigned short f2bf(float x) {
  unsigned int u = __float_as_uint(x);
  u = (u + 0x7fffu + ((u >> 16) & 1u)) >> 16;
  return (unsigned short)u;
}

// async global->LDS, 16 bytes per lane; LDS dest is wave-uniform base + lane*16
__device__ __forceinline__ void gload16(const unsigned short* g, unsigned short* l) {
  __builtin_amdgcn_global_load_lds(
      (const __attribute__((address_space(1))) unsigned int*)g,
      (__attribute__((address_space(3))) unsigned int*)l, 16, 0, 0);
}

// ---------------- state init ----------------
__global__ void k_init(int* visits, int* active, float* ent) {
  int t = threadIdx.x;
  if (t < NB * NE) visits[t] = 0;
  if (t < NB) active[t] = 1;
  if (t == 0) *ent = 0.f;
}

// ---------------- fused fp32 -> bf16 cast for the 5 weight tensors ----------------
__device__ __forceinline__ void cast8(const float* s, unsigned short* d, int j) {
  const float4* s4 = (const float4*)s;
  float4 a = s4[j * 2], b = s4[j * 2 + 1];
  short8 v;
  v[0] = (short)f2bf(a.x); v[1] = (short)f2bf(a.y);
  v[2] = (short)f2bf(a.z); v[3] = (short)f2bf(a.w);
  v[4] = (short)f2bf(b.x); v[5] = (short)f2bf(b.y);
  v[6] = (short)f2bf(b.z); v[7] = (short)f2bf(b.w);
  *(short8*)&d[(size_t)j * 8] = v;
}

__global__ __launch_bounds__(256) void k_cast5(
    const float* s0, unsigned short* d0, int n0,
    const float* s1, unsigned short* d1, int n1,
    const float* s2, unsigned short* d2, int n2,
    const float* s3, unsigned short* d3, int n3,
    const float* s4, unsigned short* d4, int n4) {
  int j = blockIdx.x * 256 + threadIdx.x;
  if (j < n0) { cast8(s0, d0, j); return; }
  j -= n0;
  if (j < n1) { cast8(s1, d1, j); return; }
  j -= n1;
  if (j < n2) { cast8(s2, d2, j); return; }
  j -= n2;
  if (j < n3) { cast8(s3, d3, j); return; }
  j -= n3;
  if (j < n4) cast8(s4, d4, j);
}

// ---------------- embedding (fp32 + bf16 mirror), 64 threads/row ----------------
__global__ __launch_bounds__(64) void k_embed(const int* __restrict__ ids,
                                              const float* __restrict__ emb,
                                              const float* __restrict__ pe,
                                              float* __restrict__ rep,
                                              unsigned short* __restrict__ repb) {
  int bs = blockIdx.x;               // b*NS + s
  int s = bs & (NS - 1);
  int id = ids[bs];
  const float sc = (id != 0) ? 22.627416997969522f : 0.f;  // sqrt(512), pad row zeroed
  const float* er = emb + (size_t)id * ND;
  const float* per = pe + (size_t)s * ND;
  float* out = rep + (size_t)bs * ND;
  unsigned short* outb = repb + (size_t)bs * ND;
  int d = threadIdx.x * 8;
  float4 e0 = *(const float4*)&er[d], e1 = *(const float4*)&er[d + 4];
  float4 p0 = *(const float4*)&per[d], p1 = *(const float4*)&per[d + 4];
  float4 o0 = {e0.x * sc + p0.x, e0.y * sc + p0.y, e0.z * sc + p0.z, e0.w * sc + p0.w};
  float4 o1 = {e1.x * sc + p1.x, e1.y * sc + p1.y, e1.z * sc + p1.z, e1.w * sc + p1.w};
  *(float4*)&out[d] = o0;
  *(float4*)&out[d + 4] = o1;
  short8 v;
  v[0] = (short)f2bf(o0.x); v[1] = (short)f2bf(o0.y);
  v[2] = (short)f2bf(o0.z); v[3] = (short)f2bf(o0.w);
  v[4] = (short)f2bf(o1.x); v[5] = (short)f2bf(o1.y);
  v[6] = (short)f2bf(o1.z); v[7] = (short)f2bf(o1.w);
  *(short8*)&outb[d] = v;
}

// ---------------- summary = rep.mean(1): grid (ND/64, NB) ----------------
__global__ __launch_bounds__(256) void k_summary(const float* __restrict__ rep,
                                                 float* __restrict__ summ) {
  int b = blockIdx.y;
  int t = threadIdx.x;
  int d = blockIdx.x * 64 + (t & 63);
  int sq = t >> 6;
  const float* r = rep + ((size_t)b * NS + sq * 64) * ND + d;
  float acc = 0.f;
  for (int s = 0; s < 64; ++s) acc += r[(size_t)s * ND];
  __shared__ float red[4][64];
  red[sq][t & 63] = acc;
  __syncthreads();
  if (t < 64)
    summ[b * ND + blockIdx.x * 64 + t] =
        (red[0][t] + red[1][t] + red[2][t] + red[3][t]) * (1.f / NS);
}

// ---------------- router (1 block) ----------------
__global__ __launch_bounds__(256) void k_router(const float* __restrict__ summ,
                                                const float* __restrict__ rw1,
                                                const float* __restrict__ rb1,
                                                const float* __restrict__ rw2,
                                                const float* __restrict__ rb2,
                                                int* visits, int* active,
                                                int* idx, int* go, float* ent_total) {
  __shared__ float sm[NB][ND];
  __shared__ float h[NB][NRH];
  __shared__ float lg[NB][NE + 1];
  int t = threadIdx.x;
  for (int i = t; i < NB * ND; i += 256) sm[i >> 9][i & 511] = summ[i];
  __syncthreads();
  {
    const float* w = rw1 + (size_t)t * ND;
    float acc[NB];
#pragma unroll
    for (int b = 0; b < NB; ++b) acc[b] = rb1[t];
    for (int d = 0; d < ND; ++d) {
      float wv = w[d];
#pragma unroll
      for (int b = 0; b < NB; ++b) acc[b] += sm[b][d] * wv;
    }
#pragma unroll
    for (int b = 0; b < NB; ++b) h[b][t] = fmaxf(acc[b], 0.f);
  }
  __syncthreads();
  if (t < NB * (NE + 1)) {
    int b = t / (NE + 1), e = t % (NE + 1);
    const float* w = rw2 + e * NRH;
    float a = rb2[e];
    for (int r = 0; r < NRH; ++r) a += h[b][r] * w[r];
    lg[b][e] = a;
  }
  __syncthreads();
  if (t == 0) {
    int aprev[NB];
    int cnt = 0;
    for (int b = 0; b < NB; ++b) { aprev[b] = active[b]; cnt += aprev[b]; }
    float entsum = 0.f;
    for (int b = 0; b < NB; ++b) {
      float l[NE + 1];
      for (int e = 0; e < NE; ++e)
        l[e] = (visits[b * NE + e] >= MAXV) ? NEGV : lg[b][e];
      l[NE] = lg[b][NE];
      float m = l[0];
      for (int e = 1; e <= NE; ++e) m = fmaxf(m, l[e]);
      float z = 0.f, p[NE + 1];
      for (int e = 0; e <= NE; ++e) { p[e] = __expf(l[e] - m); z += p[e]; }
      float zi = 1.f / z, ent = 0.f;
      for (int e = 0; e <= NE; ++e) {
        float pp = p[e] * zi;
        ent -= pp * __logf(pp + 1e-9f);
      }
      if (aprev[b]) entsum += ent;
      int ch = 0; float bm = l[0];
      for (int e = 1; e <= NE; ++e) if (l[e] > bm) { bm = l[e]; ch = e; }
      int g = (aprev[b] && ch < NE) ? 1 : 0;
      int ix = g ? ch : 0;
      visits[b * NE + ix] += g;
      idx[b] = ix; go[b] = g; active[b] = g;
    }
    if (cnt > 0) *ent_total += entsum / (float)cnt;
  }
}

// ---------------- pure-bf16 MFMA expert GEMM with global_load_lds staging ----------------
// OUT: 0 = fp32 (Fall), 1 = bf16 (Uall), 2 = qkv-split (Qb/Kb/Vt, V transposed)
// ZFILL: zero-fill fp32 out for inactive b (needed when an ungated consumer reads it)
template <int OUT, int RELU, int ZFILL>
__global__ __launch_bounds__(256) void k_gemm(
    const unsigned short* __restrict__ Aall, int sa,
    const unsigned short* __restrict__ Wall, const float* __restrict__ ball,
    float* __restrict__ Fall, unsigned short* __restrict__ Uall, int so,
    int N, int K,
    unsigned short* __restrict__ Qb, unsigned short* __restrict__ Kb,
    unsigned short* __restrict__ Vt,
    const int* __restrict__ go, const int* __restrict__ idx) {
  int b = blockIdx.z;
  int t = threadIdx.x;
  int lane = t & 63, w = t >> 6;
  int wm = (w >> 1) * 64, wn = (w & 1) * 64;
  int bm = blockIdx.x * 128, bn = blockIdx.y * 128;
  int lrow = (lane >> 4) * 4, lcol = lane & 15;
  if (!go[b]) {
    if (ZFILL) {
      float* O = Fall + (size_t)b * so;
#pragma unroll
      for (int nf = 0; nf < 4; ++nf) {
        int col = bn + wn + nf * 16 + lcol;
#pragma unroll
        for (int mf = 0; mf < 4; ++mf)
#pragma unroll
          for (int r = 0; r < 4; ++r)
            O[(size_t)(bm + wm + mf * 16 + lrow + r) * N + col] = 0.f;
      }
    }
    return;
  }
  const unsigned short* A = Aall + (size_t)b * sa;
  const unsigned short* W = Wall + (size_t)idx[b] * N * K;
  const float* bias = ball + (size_t)idx[b] * N;

  __shared__ __align__(16) unsigned short As[128][32];
  __shared__ __align__(16) unsigned short Bs[128][32];
  f32x4 acc[4][4];
#pragma unroll
  for (int i = 0; i < 4; ++i)
#pragma unroll
    for (int j = 0; j < 4; ++j) acc[i][j] = (f32x4){0.f, 0.f, 0.f, 0.f};

  // wave w stages rows [w*32, w*32+32) of each tile; lane l -> (row=l>>2, chunk=l&3)
  unsigned short* asb = &As[w * 32][0];
  unsigned short* bsb = &Bs[w * 32][0];
  const unsigned short* ga = A + (size_t)(bm + w * 32 + (lane >> 2)) * K + (lane & 3) * 8;
  const unsigned short* gb = W + (size_t)(bn + w * 32 + (lane >> 2)) * K + (lane & 3) * 8;

  for (int k0 = 0; k0 < K; k0 += 32) {
    __syncthreads();  // prev iter's ds_reads done before overwrite
    gload16(ga + k0, asb);
    gload16(ga + k0 + 16 * (size_t)K, asb + 16 * 32);
    gload16(gb + k0, bsb);
    gload16(gb + k0 + 16 * (size_t)K, bsb + 16 * 32);
    __syncthreads();  // drains vmcnt -> tiles visible
    short8 a[4], bfr[4];
    int row0 = lane & 15, kof = (lane >> 4) * 8;
#pragma unroll
    for (int mf = 0; mf < 4; ++mf)
      a[mf] = *(const short8*)&As[wm + mf * 16 + row0][kof];
#pragma unroll
    for (int nf = 0; nf < 4; ++nf)
      bfr[nf] = *(const short8*)&Bs[wn + nf * 16 + row0][kof];
#pragma unroll
    for (int mf = 0; mf < 4; ++mf)
#pragma unroll
      for (int nf = 0; nf < 4; ++nf)
        acc[mf][nf] = __builtin_amdgcn_mfma_f32_16x16x32_bf16(a[mf], bfr[nf], acc[mf][nf], 0, 0, 0);
  }

  if (OUT == 2) {
    int seg = bn >> 9;  // 0:Q 1:K 2:V — 128-tile never crosses a 512 boundary
#pragma unroll
    for (int nf = 0; nf < 4; ++nf) {
      int col = bn + wn + nf * 16 + lcol;
      float bv = bias[col];
      if (seg < 2) {
        unsigned short* dst = (seg == 0) ? Qb : Kb;
        int cc = col - seg * 512;
#pragma unroll
        for (int mf = 0; mf < 4; ++mf)
#pragma unroll
          for (int r = 0; r < 4; ++r) {
            int row = bm + wm + mf * 16 + lrow + r;
            dst[((size_t)b * NS + row) * ND + cc] = f2bf(acc[mf][nf][r] + bv);
          }
      } else {
        int dcol = col - 1024;
#pragma unroll
        for (int mf = 0; mf < 4; ++mf) {
          int s0 = bm + wm + mf * 16 + lrow;
          unsigned long long pk =
              (unsigned long long)f2bf(acc[mf][nf][0] + bv) |
              ((unsigned long long)f2bf(acc[mf][nf][1] + bv) << 16) |
              ((unsigned long long)f2bf(acc[mf][nf][2] + bv) << 32) |
              ((unsigned long long)f2bf(acc[mf][nf][3] + bv) << 48);
          *(unsigned long long*)&Vt[((size_t)b * 512 + dcol) * 256 + s0] = pk;
        }
      }
    }
  } else {
#pragma unroll
    for (int nf = 0; nf < 4; ++nf) {
      int col = bn + wn + nf * 16 + lcol;
      float bv = bias[col];
#pragma unroll
      for (int mf = 0; mf < 4; ++mf) {
#pragma unroll
        for (int r = 0; r < 4; ++r) {
          int row = bm + wm + mf * 16 + lrow + r;
          float v = acc[mf][nf][r] + bv;
          if (RELU) v = fmaxf(v, 0.f);
          if (OUT == 0)
            Fall[(size_t)b * so + (size_t)row * N + col] = v;
          else
            Uall[(size_t)b * so + (size_t)row * N + col] = f2bf(v);
        }
      }
    }
  }
}

// ---------------- MFMA flash attention, all-bf16 IO: block per (qtile, h, b) ----------------
__global__ __launch_bounds__(256) void k_attn2(const unsigned short* __restrict__ Qb,
                                               const unsigned short* __restrict__ Kb,
                                               const unsigned short* __restrict__ Vt,
                                               unsigned short* __restrict__ ctxb,
                                               const int* __restrict__ go) {
  int b = blockIdx.z, h = blockIdx.y, qt = blockIdx.x;
  int t = threadIdx.x;
  if (!go[b]) {
    short8 z = (short8){0, 0, 0, 0, 0, 0, 0, 0};
#pragma unroll
    for (int i = 0; i < 2; ++i) {
      int task = i * 256 + t;
      int q = task >> 3, cc = task & 7;
      *(short8*)&ctxb[((size_t)b * NS + qt * 64 + q) * ND + h * NDH + cc * 8] = z;
    }
    return;
  }
  __shared__ __align__(16) unsigned short lds0[16384];  // K then P
  __shared__ __align__(16) unsigned short lds1[16384];  // V^T
  int lane = t & 63, w = t >> 6, g = lane >> 4, c = lane & 15;

  // stage K: rows k=0..255, 64 d; 8 short8 chunks per row, swizzled
#pragma unroll
  for (int i = 0; i < 8; ++i) {
    int task = i * 256 + t;
    int k = task >> 3, cc = task & 7;
    short8 v = *(const short8*)&Kb[((size_t)b * NS + k) * ND + h * NDH + cc * 8];
    *(short8*)&lds0[k * 64 + ((cc * 8) ^ ((k & 7) << 3))] = v;
  }
  // stage V^T: rows d=0..63, 256 k; 32 chunks per row, swizzled
#pragma unroll
  for (int i = 0; i < 8; ++i) {
    int task = i * 256 + t;
    int d = task >> 5, kc = task & 31;
    short8 v = *(const short8*)&Vt[((size_t)b * 512 + h * NDH + d) * 256 + kc * 8];
    *(short8*)&lds1[d * 256 + ((kc * 8) ^ ((d & 7) << 3))] = v;
  }
  // Q fragments straight from global bf16
  short8 qf[2];
  {
    const unsigned short* qp = Qb + ((size_t)b * NS + qt * 64 + w * 16 + c) * ND + h * NDH;
    qf[0] = *(const short8*)&qp[g * 8];
    qf[1] = *(const short8*)&qp[32 + g * 8];
  }
  __syncthreads();

  // S^T = K @ Q^T : key = mf*16 + g*4 + r, q = w*16 + c
  f32x4 sacc[16];
#pragma unroll
  for (int mf = 0; mf < 16; ++mf) sacc[mf] = (f32x4){0.f, 0.f, 0.f, 0.f};
#pragma unroll
  for (int mf = 0; mf < 16; ++mf) {
#pragma unroll
    for (int kd = 0; kd < 2; ++kd) {
      int row = mf * 16 + c;
      short8 kf = *(const short8*)&lds0[row * 64 + ((kd * 32 + g * 8) ^ ((row & 7) << 3))];
      sacc[mf] = __builtin_amdgcn_mfma_f32_16x16x32_bf16(kf, qf[kd], sacc[mf], 0, 0, 0);
    }
  }
  __syncthreads();  // lds0 becomes P

  float mx = -3.4e38f;
#pragma unroll
  for (int mf = 0; mf < 16; ++mf) {
#pragma unroll
    for (int r = 0; r < 4; ++r) {
      sacc[mf][r] *= 0.125f;
      mx = fmaxf(mx, sacc[mf][r]);
    }
  }
  mx = fmaxf(mx, __shfl_xor(mx, 16));
  mx = fmaxf(mx, __shfl_xor(mx, 32));
  float sum = 0.f;
#pragma unroll
  for (int mf = 0; mf < 16; ++mf)
#pragma unroll
    for (int r = 0; r < 4; ++r) {
      float p = __expf(sacc[mf][r] - mx);
      sacc[mf][r] = p;
      sum += p;
    }
  sum += __shfl_xor(sum, 16);
  sum += __shfl_xor(sum, 32);
  float zi = 1.f / sum;

  int q_l = w * 16 + c;
#pragma unroll
  for (int mf = 0; mf < 16; ++mf) {
    unsigned long long pk =
        (unsigned long long)f2bf(sacc[mf][0] * zi) |
        ((unsigned long long)f2bf(sacc[mf][1] * zi) << 16) |
        ((unsigned long long)f2bf(sacc[mf][2] * zi) << 32) |
        ((unsigned long long)f2bf(sacc[mf][3] * zi) << 48);
    *(unsigned long long*)&lds0[q_l * 256 + ((mf * 16 + g * 4) ^ ((q_l & 7) << 3))] = pk;
  }

  f32x4 cacc[4];
#pragma unroll
  for (int nf = 0; nf < 4; ++nf) cacc[nf] = (f32x4){0.f, 0.f, 0.f, 0.f};
#pragma unroll
  for (int ks = 0; ks < 8; ++ks) {
    int prow = w * 16 + c;
    short8 pf = *(const short8*)&lds0[prow * 256 + ((ks * 32 + g * 8) ^ ((prow & 7) << 3))];
#pragma unroll
    for (int nf = 0; nf < 4; ++nf) {
      int vrow = nf * 16 + c;
      short8 vf = *(const short8*)&lds1[vrow * 256 + ((ks * 32 + g * 8) ^ ((vrow & 7) << 3))];
      cacc[nf] = __builtin_amdgcn_mfma_f32_16x16x32_bf16(pf, vf, cacc[nf], 0, 0, 0);
    }
  }
#pragma unroll
  for (int nf = 0; nf < 4; ++nf)
#pragma unroll
    for (int r = 0; r < 4; ++r)
      ctxb[((size_t)b * NS + qt * 64 + w * 16 + g * 4 + r) * ND + h * NDH + nf * 16 + c] =
          f2bf(cacc[nf][r]);
}

// ---------------- residual + LayerNorm, wave-per-row, fp32 out + bf16 mirror ----------------
template <int GATED>
__global__ __launch_bounds__(256) void k_lnw(const float* __restrict__ xin,
                                             const float* __restrict__ yin,
                                             const float* __restrict__ gall,
                                             const float* __restrict__ ball,
                                             const float* __restrict__ tagall,
                                             float* __restrict__ outf,
                                             unsigned short* __restrict__ outb,
                                             const int* __restrict__ go,
                                             const int* __restrict__ idx) {
  int b = blockIdx.y;
  if (GATED && !go[b]) return;
  int w = threadIdx.x >> 6, l = threadIdx.x & 63;
  int s = blockIdx.x * 4 + w;
  size_t base = ((size_t)b * NS + s) * ND;
  int d = l * 8;
  float4 x0 = *(const float4*)&xin[base + d];
  float4 x1 = *(const float4*)&xin[base + d + 4];
  float4 y0 = *(const float4*)&yin[base + d];
  float4 y1 = *(const float4*)&yin[base + d + 4];
  float v[8] = {x0.x + y0.x, x0.y + y0.y, x0.z + y0.z, x0.w + y0.w,
                x1.x + y1.x, x1.y + y1.y, x1.z + y1.z, x1.w + y1.w};
  float sum = 0.f;
#pragma unroll
  for (int j = 0; j < 8; ++j) sum += v[j];
#pragma unroll
  for (int off = 1; off < 64; off <<= 1) sum += __shfl_xor(sum, off);
  float mu = sum * (1.f / ND);
  float var = 0.f;
#pragma unroll
  for (int j = 0; j < 8; ++j) { v[j] -= mu; var += v[j] * v[j]; }
#pragma unroll
  for (int off = 1; off < 64; off <<= 1) var += __shfl_xor(var, off);
  float rs = rsqrtf(var * (1.f / ND) + 1e-5f);
  int ix = idx[b];
  float4 g0 = *(const float4*)&gall[ix * ND + d];
  float4 g1 = *(const float4*)&gall[ix * ND + d + 4];
  float4 b0 = *(const float4*)&ball[ix * ND + d];
  float4 b1 = *(const float4*)&ball[ix * ND + d + 4];
  float gg[8] = {g0.x, g0.y, g0.z, g0.w, g1.x, g1.y, g1.z, g1.w};
  float bb[8] = {b0.x, b0.y, b0.z, b0.w, b1.x, b1.y, b1.z, b1.w};
  float o[8];
#pragma unroll
  for (int j = 0; j < 8; ++j) o[j] = v[j] * rs * gg[j] + bb[j];
  if (tagall) {
    float4 t0 = *(const float4*)&tagall[ix * ND + d];
    float4 t1 = *(const float4*)&tagall[ix * ND + d + 4];
    o[0] += t0.x; o[1] += t0.y; o[2] += t0.z; o[3] += t0.w;
    o[4] += t1.x; o[5] += t1.y; o[6] += t1.z; o[7] += t1.w;
  }
  *(float4*)&outf[base + d] = (float4){o[0], o[1], o[2], o[3]};
  *(float4*)&outf[base + d + 4] = (float4){o[4], o[5], o[6], o[7]};
  short8 ob;
#pragma unroll
  for (int j = 0; j < 8; ++j) ob[j] = (short)f2bf(o[j]);
  *(short8*)&outb[base + d] = ob;
}

// ---------------- LM head: bf16 MFMA GEMM, global_load_lds staging, XCD swizzle ----------------
// grid: 4000 flat blocks (16 bm x 250 bn)
__global__ __launch_bounds__(256) void k_lmhead_bf16(const unsigned short* __restrict__ Ab,
                                                     const unsigned short* __restrict__ Wb,
                                                     const float* __restrict__ bias,
                                                     float* __restrict__ out) {
  // bijective XCD swizzle: 4000 = 8 * 500; each XCD gets a contiguous bn range
  int id = blockIdx.x;
  int swz = (id & 7) * 500 + (id >> 3);
  int bm = (swz & 15) * 128;
  int bn = (swz >> 4) * 128;

  __shared__ __align__(16) unsigned short As[128][32];
  __shared__ __align__(16) unsigned short Bs[128][32];
  int t = threadIdx.x;
  int lane = t & 63, w = t >> 6;
  int wm = (w >> 1) * 64, wn = (w & 1) * 64;
  f32x4 acc[4][4];
#pragma unroll
  for (int i = 0; i < 4; ++i)
#pragma unroll
    for (int j = 0; j < 4; ++j) acc[i][j] = (f32x4){0.f, 0.f, 0.f, 0.f};

  unsigned short* asb = &As[w * 32][0];
  unsigned short* bsb = &Bs[w * 32][0];
  const unsigned short* ga = Ab + (size_t)(bm + w * 32 + (lane >> 2)) * ND + (lane & 3) * 8;
  const unsigned short* gb = Wb + (size_t)(bn + w * 32 + (lane >> 2)) * ND + (lane & 3) * 8;

  for (int k0 = 0; k0 < ND; k0 += 32) {
    __syncthreads();
    gload16(ga + k0, asb);
    gload16(ga + k0 + 16 * ND, asb + 16 * 32);
    gload16(gb + k0, bsb);
    gload16(gb + k0 + 16 * ND, bsb + 16 * 32);
    __syncthreads();
    short8 a[4], bfr[4];
    int row0 = lane & 15, kof = (lane >> 4) * 8;
#pragma unroll
    for (int mf = 0; mf < 4; ++mf)
      a[mf] = *(const short8*)&As[wm + mf * 16 + row0][kof];
#pragma unroll
    for (int nf = 0; nf < 4; ++nf)
      bfr[nf] = *(const short8*)&Bs[wn + nf * 16 + row0][kof];
#pragma unroll
    for (int mf = 0; mf < 4; ++mf)
#pragma unroll
      for (int nf = 0; nf < 4; ++nf)
        acc[mf][nf] = __builtin_amdgcn_mfma_f32_16x16x32_bf16(a[mf], bfr[nf], acc[mf][nf], 0, 0, 0);
  }
  int lrow = (lane >> 4) * 4, lcol = lane & 15;
#pragma unroll
  for (int nf = 0; nf < 4; ++nf) {
    int col = bn + wn + nf * 16 + lcol;
    float bv = bias[col];
#pragma unroll
    for (int mf = 0; mf < 4; ++mf) {
#pragma unroll
      for (int r = 0; r < 4; ++r) {
        int row = bm + wm + mf * 16 + lrow + r;
        out[(size_t)row * NV + col] = acc[mf][nf][r] + bv;
      }
    }
  }
}

__global__ void k_ent(const float* __restrict__ entp, float* __restrict__ dst) {
  *dst = *entp;
}

extern "C" void kernel_launch(void* const* d_in, const int* in_sizes, int n_in,
                              void* d_out, int out_size, void* d_ws, size_t ws_size,
                              hipStream_t stream) {
  const int* ids   = (const int*)d_in[0];
  const float* emb = (const float*)d_in[1];
  const float* pe  = (const float*)d_in[2];
  const float* Wqkv = (const float*)d_in[3];
  const float* bqkv = (const float*)d_in[4];
  const float* Wo   = (const float*)d_in[5];
  const float* bo   = (const float*)d_in[6];
  const float* W1   = (const float*)d_in[7];
  const float* b1   = (const float*)d_in[8];
  const float* W2   = (const float*)d_in[9];
  const float* b2   = (const float*)d_in[10];
  const float* g1   = (const float*)d_in[11];
  const float* be1  = (const float*)d_in[12];
  const float* g2   = (const float*)d_in[13];
  const float* be2  = (const float*)d_in[14];
  const float* tag  = (const float*)d_in[15];
  const float* rw1  = (const float*)d_in[16];
  const float* rb1  = (const float*)d_in[17];
  const float* rw2  = (const float*)d_in[18];
  const float* rb2  = (const float*)d_in[19];
  const float* lmw  = (const float*)d_in[20];
  const float* lmb  = (const float*)d_in[21];
  float* out = (float*)d_out;

  float* ws = (float*)d_ws;
  size_t o = 0;
  float* rep = ws + o;  o += (size_t)NB * NS * ND;   // fp32
  float* x1  = ws + o;  o += (size_t)NB * NS * ND;
  float* tmp = ws + o;  o += (size_t)NB * NS * ND;
  float* summ = ws + o; o += NB * ND;
  int* visits = (int*)(ws + o); o += 1024;
  int* active = visits + NB * NE;
  int* idx = active + NB;
  int* go = idx + NB;
  float* entp = (float*)(go + NB);

  unsigned short* us = (unsigned short*)(ws + o);
  size_t uo = 0;
  unsigned short* rep_b = us + uo; uo += (size_t)NB * NS * ND;
  unsigned short* x1_b  = us + uo; uo += (size_t)NB * NS * ND;
  unsigned short* ctx_b = us + uo; uo += (size_t)NB * NS * ND;
  unsigned short* Qb    = us + uo; uo += (size_t)NB * NS * ND;
  unsigned short* Kb    = us + uo; uo += (size_t)NB * NS * ND;
  unsigned short* Vt    = us + uo; uo += (size_t)NB * NS * ND;
  unsigned short* hid_b = us + uo; uo += (size_t)NB * NS * NFF;
  unsigned short* Wqkv_b = us + uo; uo += (size_t)NE * 3 * ND * ND;
  unsigned short* Wo_b   = us + uo; uo += (size_t)NE * ND * ND;
  unsigned short* W1_b   = us + uo; uo += (size_t)NE * NFF * ND;
  unsigned short* W2_b   = us + uo; uo += (size_t)NE * ND * NFF;
  unsigned short* lmw_b  = us + uo; uo += (size_t)NV * ND;

  k_init<<<1, 64, 0, stream>>>(visits, active, entp);

  // fused weight pre-casts (deterministic every call)
  {
    int n0 = NE * 3 * ND * ND / 8, n1 = NE * ND * ND / 8, n2 = NE * NFF * ND / 8,
        n3 = NE * ND * NFF / 8, n4 = NV * ND / 8;
    int nblk = (n0 + n1 + n2 + n3 + n4) / 256;
    k_cast5<<<nblk, 256, 0, stream>>>(Wqkv, Wqkv_b, n0, Wo, Wo_b, n1,
                                      W1, W1_b, n2, W2, W2_b, n3, lmw, lmw_b, n4);
  }

  k_embed<<<NB * NS, 64, 0, stream>>>(ids, emb, pe, rep, rep_b);

  for (int step = 0; step < 4; ++step) {
    k_summary<<<dim3(ND / 64, NB), 256, 0, stream>>>(rep, summ);
    k_router<<<1, 256, 0, stream>>>(summ, rw1, rb1, rw2, rb2,
                                    visits, active, idx, go, entp);
    // qkv: rep_b @ Wqkv^T + bqkv -> Qb/Kb bf16, Vt transposed bf16
    k_gemm<2, 0, 0><<<dim3(2, 12, NB), 256, 0, stream>>>(
        rep_b, NS * ND, Wqkv_b, bqkv, nullptr, nullptr, 0, 3 * ND, ND,
        Qb, Kb, Vt, go, idx);
    // attention (all-bf16 flash)
    k_attn2<<<dim3(4, NH, NB), 256, 0, stream>>>(Qb, Kb, Vt, ctx_b, go);
    // attn_out = ctx @ Wo^T + bo -> tmp fp32 (zero-filled for inactive: ln1 is ungated)
    k_gemm<0, 0, 1><<<dim3(2, 4, NB), 256, 0, stream>>>(
        ctx_b, NS * ND, Wo_b, bo, tmp, nullptr, NS * ND, ND, ND,
        nullptr, nullptr, nullptr, go, idx);
    // x1 = LN(rep + attn_out), fp32 + bf16 mirror (always)
    k_lnw<0><<<dim3(NS / 4, NB), 256, 0, stream>>>(rep, tmp, g1, be1, nullptr,
                                                   x1, x1_b, go, idx);
    // hid = relu(x1 @ W1^T + b1) -> bf16 only
    k_gemm<1, 1, 0><<<dim3(2, 16, NB), 256, 0, stream>>>(
        x1_b, NS * ND, W1_b, b1, nullptr, hid_b, NS * NFF, NFF, ND,
        nullptr, nullptr, nullptr, go, idx);
    // ff = hid @ W2^T + b2 -> tmp fp32 (inactive: not read by gated ln2)
    k_gemm<0, 0, 0><<<dim3(2, 4, NB), 256, 0, stream>>>(
        hid_b, NS * NFF, W2_b, b2, tmp, nullptr, NS * ND, ND, NFF,
        nullptr, nullptr, nullptr, go, idx);
    // rep = LN(x1 + ff) + tag (gated select), fp32 + bf16 mirror
    k_lnw<1><<<dim3(NS / 4, NB), 256, 0, stream>>>(x1, tmp, g2, be2, tag,
                                                   rep, rep_b, go, idx);
  }

  k_lmhead_bf16<<<4000, 256, 0, stream>>>(rep_b, lmw_b, lmb, out);
  k_ent<<<1, 1, 0, stream>>>(entp, out + (size_t)NB * NS * NV);
}

// Round 7
// 681.997 us; speedup vs baseline: 2.7592x; 1.2122x over previous
//
#include <hip/hip_runtime.h>
#include <hip/hip_bf16.h>

#define NB 8
#define NS 256
#define ND 512
#define NH 8
#define NDH 64
#define NFF 2048
#define NE 8
#define NV 32000
#define NRH 256
#define MAXV 2
#define NEGV (-1e9f)

typedef __attribute__((ext_vector_type(8))) short short8;
typedef __attribute__((ext_vector_type(4))) float f32x4;

__device__ __forceinline__ unsigned short f2bf(float x) {
  unsigned int u = __float_as_uint(x);
  u = (u + 0x7fffu + ((u >> 16) & 1u)) >> 16;
  return (unsigned short)u;
}

// async global->LDS, 16 bytes per lane; LDS dest is wave-uniform base + lane*16
__device__ __forceinline__ void gload16(const unsigned short* g, unsigned short* l) {
  __builtin_amdgcn_global_load_lds(
      (const __attribute__((address_space(1))) unsigned int*)g,
      (__attribute__((address_space(3))) unsigned int*)l, 16, 0, 0);
}

// staging-side source chunk swizzle: lane -> global 16B-chunk index within a 32-col row.
// LDS slot (row, c) holds global chunk c ^ ((row>>1)&3); row_in_16 = lane>>2, c = lane&3.
__device__ __forceinline__ int swzc(int lane) {
  return (lane & 3) ^ ((lane >> 3) & 3);
}

// ---------------- fused fp32 -> bf16 cast for the 5 weight tensors + state init ----------------
__device__ __forceinline__ void cast8(const float* s, unsigned short* d, int j) {
  const float4* s4 = (const float4*)s;
  float4 a = s4[j * 2], b = s4[j * 2 + 1];
  short8 v;
  v[0] = (short)f2bf(a.x); v[1] = (short)f2bf(a.y);
  v[2] = (short)f2bf(a.z); v[3] = (short)f2bf(a.w);
  v[4] = (short)f2bf(b.x); v[5] = (short)f2bf(b.y);
  v[6] = (short)f2bf(b.z); v[7] = (short)f2bf(b.w);
  *(short8*)&d[(size_t)j * 8] = v;
}

__global__ __launch_bounds__(256) void k_cast5(
    const float* s0, unsigned short* d0, int n0,
    const float* s1, unsigned short* d1, int n1,
    const float* s2, unsigned short* d2, int n2,
    const float* s3, unsigned short* d3, int n3,
    const float* s4, unsigned short* d4, int n4,
    int* visits, int* active, float* entp) {
  if (blockIdx.x == 0) {
    if (threadIdx.x < NB * NE) visits[threadIdx.x] = 0;
    if (threadIdx.x < NB) active[threadIdx.x] = 1;
    if (threadIdx.x == 0) *entp = 0.f;
  }
  int j = blockIdx.x * 256 + threadIdx.x;
  if (j < n0) { cast8(s0, d0, j); return; }
  j -= n0;
  if (j < n1) { cast8(s1, d1, j); return; }
  j -= n1;
  if (j < n2) { cast8(s2, d2, j); return; }
  j -= n2;
  if (j < n3) { cast8(s3, d3, j); return; }
  j -= n3;
  if (j < n4) cast8(s4, d4, j);
}

// ---------------- embedding (fp32 + bf16 mirror), 64 threads/row ----------------
__global__ __launch_bounds__(64) void k_embed(const int* __restrict__ ids,
                                              const float* __restrict__ emb,
                                              const float* __restrict__ pe,
                                              float* __restrict__ rep,
                                              unsigned short* __restrict__ repb) {
  int bs = blockIdx.x;               // b*NS + s
  int s = bs & (NS - 1);
  int id = ids[bs];
  const float sc = (id != 0) ? 22.627416997969522f : 0.f;  // sqrt(512), pad row zeroed
  const float* er = emb + (size_t)id * ND;
  const float* per = pe + (size_t)s * ND;
  float* out = rep + (size_t)bs * ND;
  unsigned short* outb = repb + (size_t)bs * ND;
  int d = threadIdx.x * 8;
  float4 e0 = *(const float4*)&er[d], e1 = *(const float4*)&er[d + 4];
  float4 p0 = *(const float4*)&per[d], p1 = *(const float4*)&per[d + 4];
  float4 o0 = {e0.x * sc + p0.x, e0.y * sc + p0.y, e0.z * sc + p0.z, e0.w * sc + p0.w};
  float4 o1 = {e1.x * sc + p1.x, e1.y * sc + p1.y, e1.z * sc + p1.z, e1.w * sc + p1.w};
  *(float4*)&out[d] = o0;
  *(float4*)&out[d + 4] = o1;
  short8 v;
  v[0] = (short)f2bf(o0.x); v[1] = (short)f2bf(o0.y);
  v[2] = (short)f2bf(o0.z); v[3] = (short)f2bf(o0.w);
  v[4] = (short)f2bf(o1.x); v[5] = (short)f2bf(o1.y);
  v[6] = (short)f2bf(o1.z); v[7] = (short)f2bf(o1.w);
  *(short8*)&outb[d] = v;
}

// ---------------- summary = rep.mean(1): grid (ND/64, NB) ----------------
__global__ __launch_bounds__(256) void k_summary(const float* __restrict__ rep,
                                                 float* __restrict__ summ) {
  int b = blockIdx.y;
  int t = threadIdx.x;
  int d = blockIdx.x * 64 + (t & 63);
  int sq = t >> 6;
  const float* r = rep + ((size_t)b * NS + sq * 64) * ND + d;
  float acc = 0.f;
  for (int s = 0; s < 64; ++s) acc += r[(size_t)s * ND];
  __shared__ float red[4][64];
  red[sq][t & 63] = acc;
  __syncthreads();
  if (t < 64)
    summ[b * ND + blockIdx.x * 64 + t] =
        (red[0][t] + red[1][t] + red[2][t] + red[3][t]) * (1.f / NS);
}

// ---------------- router (1 block) ----------------
__global__ __launch_bounds__(256) void k_router(const float* __restrict__ summ,
                                                const float* __restrict__ rw1,
                                                const float* __restrict__ rb1,
                                                const float* __restrict__ rw2,
                                                const float* __restrict__ rb2,
                                                int* visits, int* active,
                                                int* idx, int* go, float* ent_total) {
  __shared__ float sm[NB][ND];
  __shared__ float h[NB][NRH];
  __shared__ float lg[NB][NE + 1];
  int t = threadIdx.x;
  for (int i = t; i < NB * ND; i += 256) sm[i >> 9][i & 511] = summ[i];
  __syncthreads();
  {
    const float* w = rw1 + (size_t)t * ND;
    float acc[NB];
#pragma unroll
    for (int b = 0; b < NB; ++b) acc[b] = rb1[t];
    for (int d = 0; d < ND; ++d) {
      float wv = w[d];
#pragma unroll
      for (int b = 0; b < NB; ++b) acc[b] += sm[b][d] * wv;
    }
#pragma unroll
    for (int b = 0; b < NB; ++b) h[b][t] = fmaxf(acc[b], 0.f);
  }
  __syncthreads();
  if (t < NB * (NE + 1)) {
    int b = t / (NE + 1), e = t % (NE + 1);
    const float* w = rw2 + e * NRH;
    float a = rb2[e];
    for (int r = 0; r < NRH; ++r) a += h[b][r] * w[r];
    lg[b][e] = a;
  }
  __syncthreads();
  if (t == 0) {
    int aprev[NB];
    int cnt = 0;
    for (int b = 0; b < NB; ++b) { aprev[b] = active[b]; cnt += aprev[b]; }
    float entsum = 0.f;
    for (int b = 0; b < NB; ++b) {
      float l[NE + 1];
      for (int e = 0; e < NE; ++e)
        l[e] = (visits[b * NE + e] >= MAXV) ? NEGV : lg[b][e];
      l[NE] = lg[b][NE];
      float m = l[0];
      for (int e = 1; e <= NE; ++e) m = fmaxf(m, l[e]);
      float z = 0.f, p[NE + 1];
      for (int e = 0; e <= NE; ++e) { p[e] = __expf(l[e] - m); z += p[e]; }
      float zi = 1.f / z, ent = 0.f;
      for (int e = 0; e <= NE; ++e) {
        float pp = p[e] * zi;
        ent -= pp * __logf(pp + 1e-9f);
      }
      if (aprev[b]) entsum += ent;
      int ch = 0; float bm = l[0];
      for (int e = 1; e <= NE; ++e) if (l[e] > bm) { bm = l[e]; ch = e; }
      int g = (aprev[b] && ch < NE) ? 1 : 0;
      int ix = g ? ch : 0;
      visits[b * NE + ix] += g;
      idx[b] = ix; go[b] = g; active[b] = g;
    }
    if (cnt > 0) *ent_total += entsum / (float)cnt;
  }
}

// ---------------- 64x64-tile bf16 MFMA expert GEMM, 2-phase dbuf + gload_lds ----------------
// OUT: 0 = fp32 (Fall), 1 = bf16 (Uall), 2 = qkv-split (Qb/Kb/Vt, V transposed)
template <int OUT, int RELU, int ZFILL>
__global__ __launch_bounds__(256) void k_gemm64(
    const unsigned short* __restrict__ Aall, int sa,
    const unsigned short* __restrict__ Wall, const float* __restrict__ ball,
    float* __restrict__ Fall, unsigned short* __restrict__ Uall, int so,
    int N, int K,
    unsigned short* __restrict__ Qb, unsigned short* __restrict__ Kb,
    unsigned short* __restrict__ Vt,
    const int* __restrict__ go, const int* __restrict__ idx) {
  int b = blockIdx.z;
  int t = threadIdx.x;
  int lane = t & 63, w = t >> 6;
  int wm = (w >> 1) * 32, wn = (w & 1) * 32;
  int bm = blockIdx.x * 64, bn = blockIdx.y * 64;
  int lrow = (lane >> 4) * 4, lcol = lane & 15;
  if (!go[b]) {
    if (ZFILL) {
      float* O = Fall + (size_t)b * so;
#pragma unroll
      for (int nf = 0; nf < 2; ++nf) {
        int col = bn + wn + nf * 16 + lcol;
#pragma unroll
        for (int mf = 0; mf < 2; ++mf)
#pragma unroll
          for (int r = 0; r < 4; ++r)
            O[(size_t)(bm + wm + mf * 16 + lrow + r) * N + col] = 0.f;
      }
    }
    return;
  }
  const unsigned short* A = Aall + (size_t)b * sa;
  const unsigned short* W = Wall + (size_t)idx[b] * N * K;
  const float* bias = ball + (size_t)idx[b] * N;

  __shared__ __align__(16) unsigned short As[2][64][32];
  __shared__ __align__(16) unsigned short Bs[2][64][32];
  f32x4 acc[2][2];
#pragma unroll
  for (int i = 0; i < 2; ++i)
#pragma unroll
    for (int j = 0; j < 2; ++j) acc[i][j] = (f32x4){0.f, 0.f, 0.f, 0.f};

  // wave w stages rows [w*16, w*16+16); lane l -> row w*16 + (l>>2), src chunk swzc(l)
  const unsigned short* ga = A + (size_t)(bm + w * 16 + (lane >> 2)) * K + swzc(lane) * 8;
  const unsigned short* gb = W + (size_t)(bn + w * 16 + (lane >> 2)) * K + swzc(lane) * 8;

  gload16(ga, &As[0][w * 16][0]);
  gload16(gb, &Bs[0][w * 16][0]);
  __syncthreads();

  int nk = K >> 5;
  int row0 = lane & 15;
  int cs = ((lane >> 4) ^ ((row0 >> 1) & 3)) * 8;  // swizzled 16B-chunk slot
  for (int it = 0; it < nk; ++it) {
    int cur = it & 1;
    if (it + 1 < nk) {
      gload16(ga + (it + 1) * 32, &As[cur ^ 1][w * 16][0]);
      gload16(gb + (it + 1) * 32, &Bs[cur ^ 1][w * 16][0]);
    }
    short8 a[2], bfr[2];
#pragma unroll
    for (int mf = 0; mf < 2; ++mf)
      a[mf] = *(const short8*)&As[cur][wm + mf * 16 + row0][cs];
#pragma unroll
    for (int nf = 0; nf < 2; ++nf)
      bfr[nf] = *(const short8*)&Bs[cur][wn + nf * 16 + row0][cs];
#pragma unroll
    for (int mf = 0; mf < 2; ++mf)
#pragma unroll
      for (int nf = 0; nf < 2; ++nf)
        acc[mf][nf] = __builtin_amdgcn_mfma_f32_16x16x32_bf16(a[mf], bfr[nf], acc[mf][nf], 0, 0, 0);
    __syncthreads();  // stage gloads landed; all reads of cur done
  }

  if (OUT == 2) {
    int seg = bn >> 9;  // 0:Q 1:K 2:V — 64-tile never crosses a 512 boundary
#pragma unroll
    for (int nf = 0; nf < 2; ++nf) {
      int col = bn + wn + nf * 16 + lcol;
      float bv = bias[col];
      if (seg < 2) {
        unsigned short* dst = (seg == 0) ? Qb : Kb;
        int cc = col - seg * 512;
#pragma unroll
        for (int mf = 0; mf < 2; ++mf)
#pragma unroll
          for (int r = 0; r < 4; ++r) {
            int row = bm + wm + mf * 16 + lrow + r;
            dst[((size_t)b * NS + row) * ND + cc] = f2bf(acc[mf][nf][r] + bv);
          }
      } else {
        int dcol = col - 1024;
#pragma unroll
        for (int mf = 0; mf < 2; ++mf) {
          int s0 = bm + wm + mf * 16 + lrow;
          unsigned long long pk =
              (unsigned long long)f2bf(acc[mf][nf][0] + bv) |
              ((unsigned long long)f2bf(acc[mf][nf][1] + bv) << 16) |
              ((unsigned long long)f2bf(acc[mf][nf][2] + bv) << 32) |
              ((unsigned long long)f2bf(acc[mf][nf][3] + bv) << 48);
          *(unsigned long long*)&Vt[((size_t)b * 512 + dcol) * 256 + s0] = pk;
        }
      }
    }
  } else {
#pragma unroll
    for (int nf = 0; nf < 2; ++nf) {
      int col = bn + wn + nf * 16 + lcol;
      float bv = bias[col];
#pragma unroll
      for (int mf = 0; mf < 2; ++mf) {
#pragma unroll
        for (int r = 0; r < 4; ++r) {
          int row = bm + wm + mf * 16 + lrow + r;
          float v = acc[mf][nf][r] + bv;
          if (RELU) v = fmaxf(v, 0.f);
          if (OUT == 0)
            Fall[(size_t)b * so + (size_t)row * N + col] = v;
          else
            Uall[(size_t)b * so + (size_t)row * N + col] = f2bf(v);
        }
      }
    }
  }
}

// ---------------- MFMA flash attention, all-bf16 IO: block per (qtile, h, b) ----------------
__global__ __launch_bounds__(256) void k_attn2(const unsigned short* __restrict__ Qb,
                                               const unsigned short* __restrict__ Kb,
                                               const unsigned short* __restrict__ Vt,
                                               unsigned short* __restrict__ ctxb,
                                               const int* __restrict__ go) {
  int b = blockIdx.z, h = blockIdx.y, qt = blockIdx.x;
  int t = threadIdx.x;
  if (!go[b]) {
    short8 z = (short8){0, 0, 0, 0, 0, 0, 0, 0};
#pragma unroll
    for (int i = 0; i < 2; ++i) {
      int task = i * 256 + t;
      int q = task >> 3, cc = task & 7;
      *(short8*)&ctxb[((size_t)b * NS + qt * 64 + q) * ND + h * NDH + cc * 8] = z;
    }
    return;
  }
  __shared__ __align__(16) unsigned short lds0[16384];  // K then P
  __shared__ __align__(16) unsigned short lds1[16384];  // V^T
  int lane = t & 63, w = t >> 6, g = lane >> 4, c = lane & 15;

#pragma unroll
  for (int i = 0; i < 8; ++i) {
    int task = i * 256 + t;
    int k = task >> 3, cc = task & 7;
    short8 v = *(const short8*)&Kb[((size_t)b * NS + k) * ND + h * NDH + cc * 8];
    *(short8*)&lds0[k * 64 + ((cc * 8) ^ ((k & 7) << 3))] = v;
  }
#pragma unroll
  for (int i = 0; i < 8; ++i) {
    int task = i * 256 + t;
    int d = task >> 5, kc = task & 31;
    short8 v = *(const short8*)&Vt[((size_t)b * 512 + h * NDH + d) * 256 + kc * 8];
    *(short8*)&lds1[d * 256 + ((kc * 8) ^ ((d & 7) << 3))] = v;
  }
  short8 qf[2];
  {
    const unsigned short* qp = Qb + ((size_t)b * NS + qt * 64 + w * 16 + c) * ND + h * NDH;
    qf[0] = *(const short8*)&qp[g * 8];
    qf[1] = *(const short8*)&qp[32 + g * 8];
  }
  __syncthreads();

  f32x4 sacc[16];
#pragma unroll
  for (int mf = 0; mf < 16; ++mf) sacc[mf] = (f32x4){0.f, 0.f, 0.f, 0.f};
#pragma unroll
  for (int mf = 0; mf < 16; ++mf) {
#pragma unroll
    for (int kd = 0; kd < 2; ++kd) {
      int row = mf * 16 + c;
      short8 kf = *(const short8*)&lds0[row * 64 + ((kd * 32 + g * 8) ^ ((row & 7) << 3))];
      sacc[mf] = __builtin_amdgcn_mfma_f32_16x16x32_bf16(kf, qf[kd], sacc[mf], 0, 0, 0);
    }
  }
  __syncthreads();  // lds0 becomes P

  float mx = -3.4e38f;
#pragma unroll
  for (int mf = 0; mf < 16; ++mf) {
#pragma unroll
    for (int r = 0; r < 4; ++r) {
      sacc[mf][r] *= 0.125f;
      mx = fmaxf(mx, sacc[mf][r]);
    }
  }
  mx = fmaxf(mx, __shfl_xor(mx, 16));
  mx = fmaxf(mx, __shfl_xor(mx, 32));
  float sum = 0.f;
#pragma unroll
  for (int mf = 0; mf < 16; ++mf)
#pragma unroll
    for (int r = 0; r < 4; ++r) {
      float p = __expf(sacc[mf][r] - mx);
      sacc[mf][r] = p;
      sum += p;
    }
  sum += __shfl_xor(sum, 16);
  sum += __shfl_xor(sum, 32);
  float zi = 1.f / sum;

  int q_l = w * 16 + c;
#pragma unroll
  for (int mf = 0; mf < 16; ++mf) {
    unsigned long long pk =
        (unsigned long long)f2bf(sacc[mf][0] * zi) |
        ((unsigned long long)f2bf(sacc[mf][1] * zi) << 16) |
        ((unsigned long long)f2bf(sacc[mf][2] * zi) << 32) |
        ((unsigned long long)f2bf(sacc[mf][3] * zi) << 48);
    *(unsigned long long*)&lds0[q_l * 256 + ((mf * 16 + g * 4) ^ ((q_l & 7) << 3))] = pk;
  }

  f32x4 cacc[4];
#pragma unroll
  for (int nf = 0; nf < 4; ++nf) cacc[nf] = (f32x4){0.f, 0.f, 0.f, 0.f};
#pragma unroll
  for (int ks = 0; ks < 8; ++ks) {
    int prow = w * 16 + c;
    short8 pf = *(const short8*)&lds0[prow * 256 + ((ks * 32 + g * 8) ^ ((prow & 7) << 3))];
#pragma unroll
    for (int nf = 0; nf < 4; ++nf) {
      int vrow = nf * 16 + c;
      short8 vf = *(const short8*)&lds1[vrow * 256 + ((ks * 32 + g * 8) ^ ((vrow & 7) << 3))];
      cacc[nf] = __builtin_amdgcn_mfma_f32_16x16x32_bf16(pf, vf, cacc[nf], 0, 0, 0);
    }
  }
#pragma unroll
  for (int nf = 0; nf < 4; ++nf)
#pragma unroll
    for (int r = 0; r < 4; ++r)
      ctxb[((size_t)b * NS + qt * 64 + w * 16 + g * 4 + r) * ND + h * NDH + nf * 16 + c] =
          f2bf(cacc[nf][r]);
}

// ---------------- residual + LayerNorm, wave-per-row, fp32 out + bf16 mirror ----------------
template <int GATED>
__global__ __launch_bounds__(256) void k_lnw(const float* __restrict__ xin,
                                             const float* __restrict__ yin,
                                             const float* __restrict__ gall,
                                             const float* __restrict__ ball,
                                             const float* __restrict__ tagall,
                                             float* __restrict__ outf,
                                             unsigned short* __restrict__ outb,
                                             const int* __restrict__ go,
                                             const int* __restrict__ idx) {
  int b = blockIdx.y;
  if (GATED && !go[b]) return;
  int w = threadIdx.x >> 6, l = threadIdx.x & 63;
  int s = blockIdx.x * 4 + w;
  size_t base = ((size_t)b * NS + s) * ND;
  int d = l * 8;
  float4 x0 = *(const float4*)&xin[base + d];
  float4 x1 = *(const float4*)&xin[base + d + 4];
  float4 y0 = *(const float4*)&yin[base + d];
  float4 y1 = *(const float4*)&yin[base + d + 4];
  float v[8] = {x0.x + y0.x, x0.y + y0.y, x0.z + y0.z, x0.w + y0.w,
                x1.x + y1.x, x1.y + y1.y, x1.z + y1.z, x1.w + y1.w};
  float sum = 0.f;
#pragma unroll
  for (int j = 0; j < 8; ++j) sum += v[j];
#pragma unroll
  for (int off = 1; off < 64; off <<= 1) sum += __shfl_xor(sum, off);
  float mu = sum * (1.f / ND);
  float var = 0.f;
#pragma unroll
  for (int j = 0; j < 8; ++j) { v[j] -= mu; var += v[j] * v[j]; }
#pragma unroll
  for (int off = 1; off < 64; off <<= 1) var += __shfl_xor(var, off);
  float rs = rsqrtf(var * (1.f / ND) + 1e-5f);
  int ix = idx[b];
  float4 g0 = *(const float4*)&gall[ix * ND + d];
  float4 g1 = *(const float4*)&gall[ix * ND + d + 4];
  float4 b0 = *(const float4*)&ball[ix * ND + d];
  float4 b1 = *(const float4*)&ball[ix * ND + d + 4];
  float gg[8] = {g0.x, g0.y, g0.z, g0.w, g1.x, g1.y, g1.z, g1.w};
  float bb[8] = {b0.x, b0.y, b0.z, b0.w, b1.x, b1.y, b1.z, b1.w};
  float o[8];
#pragma unroll
  for (int j = 0; j < 8; ++j) o[j] = v[j] * rs * gg[j] + bb[j];
  if (tagall) {
    float4 t0 = *(const float4*)&tagall[ix * ND + d];
    float4 t1 = *(const float4*)&tagall[ix * ND + d + 4];
    o[0] += t0.x; o[1] += t0.y; o[2] += t0.z; o[3] += t0.w;
    o[4] += t1.x; o[5] += t1.y; o[6] += t1.z; o[7] += t1.w;
  }
  *(float4*)&outf[base + d] = (float4){o[0], o[1], o[2], o[3]};
  *(float4*)&outf[base + d + 4] = (float4){o[4], o[5], o[6], o[7]};
  short8 ob;
#pragma unroll
  for (int j = 0; j < 8; ++j) ob[j] = (short)f2bf(o[j]);
  *(short8*)&outb[base + d] = ob;
}

// ---------------- LM head: bf16 MFMA GEMM, 2-phase dbuf gload_lds, XCD swizzle ----------------
// grid: 4000 flat blocks (16 bm x 250 bn)
__global__ __launch_bounds__(256) void k_lmhead_bf16(const unsigned short* __restrict__ Ab,
                                                     const unsigned short* __restrict__ Wb,
                                                     const float* __restrict__ bias,
                                                     float* __restrict__ out,
                                                     const float* __restrict__ entp) {
  if (blockIdx.x == 0 && threadIdx.x == 0)
    out[(size_t)NB * NS * NV] = *entp;  // fused k_ent
  int id = blockIdx.x;
  int swz = (id & 7) * 500 + (id >> 3);  // bijective: 4000 = 8 * 500
  int bm = (swz & 15) * 128;
  int bn = (swz >> 4) * 128;

  __shared__ __align__(16) unsigned short As[2][128][32];
  __shared__ __align__(16) unsigned short Bs[2][128][32];
  int t = threadIdx.x;
  int lane = t & 63, w = t >> 6;
  int wm = (w >> 1) * 64, wn = (w & 1) * 64;
  f32x4 acc[4][4];
#pragma unroll
  for (int i = 0; i < 4; ++i)
#pragma unroll
    for (int j = 0; j < 4; ++j) acc[i][j] = (f32x4){0.f, 0.f, 0.f, 0.f};

  // wave w stages rows [w*32, w*32+32); two 16-row gloads per tensor
  const unsigned short* ga = Ab + (size_t)(bm + w * 32 + (lane >> 2)) * ND + swzc(lane) * 8;
  const unsigned short* gb = Wb + (size_t)(bn + w * 32 + (lane >> 2)) * ND + swzc(lane) * 8;

  gload16(ga, &As[0][w * 32][0]);
  gload16(ga + 16 * ND, &As[0][w * 32 + 16][0]);
  gload16(gb, &Bs[0][w * 32][0]);
  gload16(gb + 16 * ND, &Bs[0][w * 32 + 16][0]);
  __syncthreads();

  int row0 = lane & 15;
  int cs = ((lane >> 4) ^ ((row0 >> 1) & 3)) * 8;
  for (int it = 0; it < 16; ++it) {
    int cur = it & 1;
    if (it < 15) {
      int k0 = (it + 1) * 32;
      gload16(ga + k0, &As[cur ^ 1][w * 32][0]);
      gload16(ga + k0 + 16 * ND, &As[cur ^ 1][w * 32 + 16][0]);
      gload16(gb + k0, &Bs[cur ^ 1][w * 32][0]);
      gload16(gb + k0 + 16 * ND, &Bs[cur ^ 1][w * 32 + 16][0]);
    }
    short8 a[4], bfr[4];
#pragma unroll
    for (int mf = 0; mf < 4; ++mf)
      a[mf] = *(const short8*)&As[cur][wm + mf * 16 + row0][cs];
#pragma unroll
    for (int nf = 0; nf < 4; ++nf)
      bfr[nf] = *(const short8*)&Bs[cur][wn + nf * 16 + row0][cs];
#pragma unroll
    for (int mf = 0; mf < 4; ++mf)
#pragma unroll
      for (int nf = 0; nf < 4; ++nf)
        acc[mf][nf] = __builtin_amdgcn_mfma_f32_16x16x32_bf16(a[mf], bfr[nf], acc[mf][nf], 0, 0, 0);
    __syncthreads();
  }
  int lrow = (lane >> 4) * 4, lcol = lane & 15;
#pragma unroll
  for (int nf = 0; nf < 4; ++nf) {
    int col = bn + wn + nf * 16 + lcol;
    float bv = bias[col];
#pragma unroll
    for (int mf = 0; mf < 4; ++mf) {
#pragma unroll
      for (int r = 0; r < 4; ++r) {
        int row = bm + wm + mf * 16 + lrow + r;
        out[(size_t)row * NV + col] = acc[mf][nf][r] + bv;
      }
    }
  }
}

extern "C" void kernel_launch(void* const* d_in, const int* in_sizes, int n_in,
                              void* d_out, int out_size, void* d_ws, size_t ws_size,
                              hipStream_t stream) {
  const int* ids   = (const int*)d_in[0];
  const float* emb = (const float*)d_in[1];
  const float* pe  = (const float*)d_in[2];
  const float* Wqkv = (const float*)d_in[3];
  const float* bqkv = (const float*)d_in[4];
  const float* Wo   = (const float*)d_in[5];
  const float* bo   = (const float*)d_in[6];
  const float* W1   = (const float*)d_in[7];
  const float* b1   = (const float*)d_in[8];
  const float* W2   = (const float*)d_in[9];
  const float* b2   = (const float*)d_in[10];
  const float* g1   = (const float*)d_in[11];
  const float* be1  = (const float*)d_in[12];
  const float* g2   = (const float*)d_in[13];
  const float* be2  = (const float*)d_in[14];
  const float* tag  = (const float*)d_in[15];
  const float* rw1  = (const float*)d_in[16];
  const float* rb1  = (const float*)d_in[17];
  const float* rw2  = (const float*)d_in[18];
  const float* rb2  = (const float*)d_in[19];
  const float* lmw  = (const float*)d_in[20];
  const float* lmb  = (const float*)d_in[21];
  float* out = (float*)d_out;

  float* ws = (float*)d_ws;
  size_t o = 0;
  float* rep = ws + o;  o += (size_t)NB * NS * ND;   // fp32
  float* x1  = ws + o;  o += (size_t)NB * NS * ND;
  float* tmp = ws + o;  o += (size_t)NB * NS * ND;
  float* summ = ws + o; o += NB * ND;
  int* visits = (int*)(ws + o); o += 1024;
  int* active = visits + NB * NE;
  int* idx = active + NB;
  int* go = idx + NB;
  float* entp = (float*)(go + NB);

  unsigned short* us = (unsigned short*)(ws + o);
  size_t uo = 0;
  unsigned short* rep_b = us + uo; uo += (size_t)NB * NS * ND;
  unsigned short* x1_b  = us + uo; uo += (size_t)NB * NS * ND;
  unsigned short* ctx_b = us + uo; uo += (size_t)NB * NS * ND;
  unsigned short* Qb    = us + uo; uo += (size_t)NB * NS * ND;
  unsigned short* Kb    = us + uo; uo += (size_t)NB * NS * ND;
  unsigned short* Vt    = us + uo; uo += (size_t)NB * NS * ND;
  unsigned short* hid_b = us + uo; uo += (size_t)NB * NS * NFF;
  unsigned short* Wqkv_b = us + uo; uo += (size_t)NE * 3 * ND * ND;
  unsigned short* Wo_b   = us + uo; uo += (size_t)NE * ND * ND;
  unsigned short* W1_b   = us + uo; uo += (size_t)NE * NFF * ND;
  unsigned short* W2_b   = us + uo; uo += (size_t)NE * ND * NFF;
  unsigned short* lmw_b  = us + uo; uo += (size_t)NV * ND;

  // fused weight pre-casts + state init (deterministic every call)
  {
    int n0 = NE * 3 * ND * ND / 8, n1 = NE * ND * ND / 8, n2 = NE * NFF * ND / 8,
        n3 = NE * ND * NFF / 8, n4 = NV * ND / 8;
    int nblk = (n0 + n1 + n2 + n3 + n4) / 256;
    k_cast5<<<nblk, 256, 0, stream>>>(Wqkv, Wqkv_b, n0, Wo, Wo_b, n1,
                                      W1, W1_b, n2, W2, W2_b, n3, lmw, lmw_b, n4,
                                      visits, active, entp);
  }

  k_embed<<<NB * NS, 64, 0, stream>>>(ids, emb, pe, rep, rep_b);

  for (int step = 0; step < 4; ++step) {
    k_summary<<<dim3(ND / 64, NB), 256, 0, stream>>>(rep, summ);
    k_router<<<1, 256, 0, stream>>>(summ, rw1, rb1, rw2, rb2,
                                    visits, active, idx, go, entp);
    // qkv: rep_b @ Wqkv^T + bqkv -> Qb/Kb bf16, Vt transposed bf16
    k_gemm64<2, 0, 0><<<dim3(4, 24, NB), 256, 0, stream>>>(
        rep_b, NS * ND, Wqkv_b, bqkv, nullptr, nullptr, 0, 3 * ND, ND,
        Qb, Kb, Vt, go, idx);
    // attention (all-bf16 flash)
    k_attn2<<<dim3(4, NH, NB), 256, 0, stream>>>(Qb, Kb, Vt, ctx_b, go);
    // attn_out = ctx @ Wo^T + bo -> tmp fp32 (zero-filled for inactive: ln1 is ungated)
    k_gemm64<0, 0, 1><<<dim3(4, 8, NB), 256, 0, stream>>>(
        ctx_b, NS * ND, Wo_b, bo, tmp, nullptr, NS * ND, ND, ND,
        nullptr, nullptr, nullptr, go, idx);
    // x1 = LN(rep + attn_out), fp32 + bf16 mirror (always)
    k_lnw<0><<<dim3(NS / 4, NB), 256, 0, stream>>>(rep, tmp, g1, be1, nullptr,
                                                   x1, x1_b, go, idx);
    // hid = relu(x1 @ W1^T + b1) -> bf16 only
    k_gemm64<1, 1, 0><<<dim3(4, 32, NB), 256, 0, stream>>>(
        x1_b, NS * ND, W1_b, b1, nullptr, hid_b, NS * NFF, NFF, ND,
        nullptr, nullptr, nullptr, go, idx);
    // ff = hid @ W2^T + b2 -> tmp fp32 (inactive: not read by gated ln2)
    k_gemm64<0, 0, 0><<<dim3(4, 8, NB), 256, 0, stream>>>(
        hid_b, NS * NFF, W2_b, b2, tmp, nullptr, NS * ND, ND, NFF,
        nullptr, nullptr, nullptr, go, idx);
    // rep = LN(x1 + ff) + tag (gated select), fp32 + bf16 mirror
    k_lnw<1><<<dim3(NS / 4, NB), 256, 0, stream>>>(x1, tmp, g2, be2, tag,
                                                   rep, rep_b, go, idx);
  }

  k_lmhead_bf16<<<4000, 256, 0, stream>>>(rep_b, lmw_b, lmb, out, entp);
}